// Round 14
// baseline (1184.932 us; speedup 1.0000x reference)
//
#include <hip/hip_runtime.h>
#include <hip/hip_bf16.h>

// ---------- types ----------
typedef __attribute__((ext_vector_type(8))) short s16x8;
typedef __attribute__((ext_vector_type(4))) short s16x4;
typedef __attribute__((ext_vector_type(8))) __bf16 bf16x8;
typedef __attribute__((ext_vector_type(4))) float f32x4;
typedef __attribute__((ext_vector_type(16))) float f32x16;

__device__ __forceinline__ float b2f(short s) {
  union { float f; unsigned u; } x;
  x.u = ((unsigned)(unsigned short)s) << 16;
  return x.f;
}
__device__ __forceinline__ short f2b(float f) {
  union { float f; unsigned u; } x;
  x.f = f;
  unsigned r = x.u + 0x7fff + ((x.u >> 16) & 1);  // RNE
  return (short)(r >> 16);
}
__device__ __forceinline__ bf16x8 asbf(s16x8 v) {
  union { s16x8 s; bf16x8 b; } u; u.s = v; return u.b;
}

#define GLD16(g, l) __builtin_amdgcn_global_load_lds( \
    (const __attribute__((address_space(1))) void*)(g), \
    (__attribute__((address_space(3))) void*)(l), 16, 0, 0)

#define WAITB(N) do { \
  asm volatile("s_waitcnt vmcnt(" #N ")" ::: "memory"); \
  __builtin_amdgcn_s_barrier(); \
  asm volatile("" ::: "memory"); \
} while (0)

// ---------- weight transpose + fp32->bf16 : out[c][r] = in[r][c] ----------
__global__ __launch_bounds__(256) void transpose_cvt(
    const float* __restrict__ in, short* __restrict__ out, int R, int C) {
  __shared__ float tile[32][33];
  const int tx = threadIdx.x & 31, ty = threadIdx.x >> 5;  // 32x8
  const int c0 = blockIdx.x * 32, r0 = blockIdx.y * 32;
  #pragma unroll
  for (int i = 0; i < 32; i += 8)
    tile[ty + i][tx] = in[(size_t)(r0 + ty + i) * C + c0 + tx];
  __syncthreads();
  #pragma unroll
  for (int i = 0; i < 32; i += 8)
    out[(size_t)(c0 + ty + i) * R + r0 + tx] = f2b(tile[tx][ty + i]);
}

// ---------- layernorm: fp32 [rows][1024] -> bf16 ----------
__global__ __launch_bounds__(256) void ln_kernel(
    const float* __restrict__ x, const float* __restrict__ gw,
    const float* __restrict__ gb, short* __restrict__ out) {
  const int row = blockIdx.x;
  const int tid = threadIdx.x;
  const float4 v = ((const float4*)(x + (size_t)row * 1024))[tid];
  float s = v.x + v.y + v.z + v.w;
  float s2 = v.x * v.x + v.y * v.y + v.z * v.z + v.w * v.w;
  #pragma unroll
  for (int o = 32; o > 0; o >>= 1) {
    s += __shfl_xor(s, o);
    s2 += __shfl_xor(s2, o);
  }
  __shared__ float red[2][4];
  const int lane = tid & 63, wid = tid >> 6;
  if (lane == 0) { red[0][wid] = s; red[1][wid] = s2; }
  __syncthreads();
  s = red[0][0] + red[0][1] + red[0][2] + red[0][3];
  s2 = red[1][0] + red[1][1] + red[1][2] + red[1][3];
  const float mu = s * (1.f / 1024.f);
  const float rstd = rsqrtf(s2 * (1.f / 1024.f) - mu * mu + 1e-5f);
  const float4 wv4 = ((const float4*)gw)[tid];
  const float4 bv4 = ((const float4*)gb)[tid];
  s16x4 o4;
  o4.x = f2b((v.x - mu) * rstd * wv4.x + bv4.x);
  o4.y = f2b((v.y - mu) * rstd * wv4.y + bv4.y);
  o4.z = f2b((v.z - mu) * rstd * wv4.z + bv4.z);
  o4.w = f2b((v.w - mu) * rstd * wv4.w + bv4.w);
  *(s16x4*)(out + (size_t)row * 1024 + tid * 4) = o4;
}

// ---------- layernorm, bf16 input: [rows][1024] bf16 -> bf16 ----------
__global__ __launch_bounds__(256) void ln_kernel_b(
    const short* __restrict__ x, const float* __restrict__ gw,
    const float* __restrict__ gb, short* __restrict__ out) {
  const int row = blockIdx.x;
  const int tid = threadIdx.x;
  const s16x4 xv = *(const s16x4*)(x + (size_t)row * 1024 + tid * 4);
  float v0 = b2f(xv.x), v1 = b2f(xv.y), v2 = b2f(xv.z), v3 = b2f(xv.w);
  float s = v0 + v1 + v2 + v3;
  float s2 = v0 * v0 + v1 * v1 + v2 * v2 + v3 * v3;
  #pragma unroll
  for (int o = 32; o > 0; o >>= 1) {
    s += __shfl_xor(s, o);
    s2 += __shfl_xor(s2, o);
  }
  __shared__ float red[2][4];
  const int lane = tid & 63, wid = tid >> 6;
  if (lane == 0) { red[0][wid] = s; red[1][wid] = s2; }
  __syncthreads();
  s = red[0][0] + red[0][1] + red[0][2] + red[0][3];
  s2 = red[1][0] + red[1][1] + red[1][2] + red[1][3];
  const float mu = s * (1.f / 1024.f);
  const float rstd = rsqrtf(s2 * (1.f / 1024.f) - mu * mu + 1e-5f);
  const float4 wv4 = ((const float4*)gw)[tid];
  const float4 bv4 = ((const float4*)gb)[tid];
  s16x4 o4;
  o4.x = f2b((v0 - mu) * rstd * wv4.x + bv4.x);
  o4.y = f2b((v1 - mu) * rstd * wv4.y + bv4.y);
  o4.z = f2b((v2 - mu) * rstd * wv4.z + bv4.z);
  o4.w = f2b((v3 - mu) * rstd * wv4.w + bv4.w);
  *(s16x4*)(out + (size_t)row * 1024 + tid * 4) = o4;
}

// ---------- 256x256 bf16 MFMA GEMM: 32x32x16 MFMA variant ----------
// r14 change: 16x16x32 -> 32x32x16 MFMA (uBench 2075 -> 2382 TF: -13% pipe
// cycles for identical FLOPs and identical LDS bytes). LDS layout, swizzle,
// staging, ledger, mapping all byte-identical to r11/r13.
// Operand lane map (family pattern, validated by working 16x16 kernel):
//   A/B: row|col = lane&31, k = 8*(lane>>5)+e  (window w: k += 16w)
//   C/D: col = lane&31, row = (reg&3)+8*(reg>>2)+4*(lane>>5)  [m74/m101]
// Read slot: q = 2w+(lane>>5); s = ((row&1)<<2|q)^((row>>1)&7) — same slot
// statistics as the 16x16 read (8 lanes/slot-value) -> conflicts stay 0.

enum { EPI_QKV = 0, EPI_RES = 1, EPI_GELU = 2, EPI_FC2 = 3 };

#define PHASE(BUFB, MH, KS, LOADB) do { \
    const int ab = (BUFB) + (KS) * 16384; \
    const int bb = (BUFB) + 32768 + (KS) * 16384; \
    if (LOADB) { \
      _Pragma("unroll") \
      for (int cf = 0; cf < 2; cf++) \
        _Pragma("unroll") \
        for (int w = 0; w < 2; w++) { \
          const int row = wnCol + cf * 32 + l31; \
          const int g = row >> 1; \
          const int q = 2 * w + lh; \
          const int s = (((row & 1) << 2) | q) ^ (g & 7); \
          bfvw[cf][w] = *(const bf16x8*)(ldsc + bb + g * 128 + s * 16); \
        } \
    } \
    bf16x8 af[2][2]; \
    _Pragma("unroll") \
    for (int rf = 0; rf < 2; rf++) \
      _Pragma("unroll") \
      for (int w = 0; w < 2; w++) { \
        const int row = wmRow + ((MH) * 2 + rf) * 32 + l31; \
        const int g = row >> 1; \
        const int q = 2 * w + lh; \
        const int s = (((row & 1) << 2) | q) ^ (g & 7); \
        af[rf][w] = *(const bf16x8*)(ldsc + ab + g * 128 + s * 16); \
      } \
    __builtin_amdgcn_s_setprio(1); \
    _Pragma("unroll") \
    for (int w = 0; w < 2; w++) \
      _Pragma("unroll") \
      for (int rf = 0; rf < 2; rf++) \
        _Pragma("unroll") \
        for (int cf = 0; cf < 2; cf++) \
          acc[(MH) * 2 + rf][cf] = __builtin_amdgcn_mfma_f32_32x32x16_bf16( \
              af[rf][w], bfvw[cf][w], acc[(MH) * 2 + rf][cf], 0, 0, 0); \
    __builtin_amdgcn_s_setprio(0); \
  } while (0)

template <int EPI>
__global__ __launch_bounds__(512, 2) void gemm256(
    const short* __restrict__ A, int lda,
    const short* __restrict__ Bt, int K, int ldo, int gx,
    const float* __restrict__ bias,
    const void* __restrict__ resid,
    void* __restrict__ outp) {
  __shared__ alignas(16) short lds[65536];  // 128 KiB
  const int tid = threadIdx.x;
  const int lane = tid & 63, wave = tid >> 6;
  // T1: bijective XCD swizzle (grid % 8 == 0 for all launches)
  const int cpx = (int)gridDim.x >> 3;
  const int bid = ((int)blockIdx.x & 7) * cpx + ((int)blockIdx.x >> 3);
  // L2 super-tile mapping: 32-block groups of 8bm x 4bn
  const int sgx = gx >> 3;
  const int grp = bid >> 5;
  const int sm = grp % sgx, sn = grp / sgx;
  const int bm = (sm * 8 + (bid & 7)) * 256;
  const int bn = (sn * 4 + ((bid & 31) >> 3)) * 256;
  const int wmRow = (wave >> 2) * 128;
  const int wnCol = (wave & 3) * 64;
  const int l31 = lane & 31, lh = lane >> 5;

  // staging constants: inverse-swizzled global source, linear LDS dest
  const int sg = tid >> 3;
  const int s0 = (tid & 7) ^ (sg & 7);
  const int srow = 2 * sg + (s0 >> 2);   // load 0 row; load 1 adds 128
  const int scol = (s0 & 3) * 8;
  const int sdst = tid * 16;

  const char* ldsc = (const char*)lds;
  char* ldsw = (char*)lds;

  f32x16 acc[4][2] = {};
  bf16x8 bfvw[2][2];

  auto stageA = [&](int bufb, int kh, int kk) {
    const short* g = A + (size_t)(bm + srow) * lda + kk + kh * 32 + scol;
    char* l = ldsw + bufb + kh * 16384 + sdst;
    GLD16(g, l);
    GLD16(g + (size_t)128 * lda, l + 8192);
  };
  auto stageB = [&](int bufb, int kh, int kk) {
    const short* g = Bt + (size_t)(bn + srow) * K + kk + kh * 32 + scol;
    char* l = ldsw + bufb + 32768 + kh * 16384 + sdst;
    GLD16(g, l);
    GLD16(g + (size_t)128 * K, l + 8192);
  };

  const int NT = K >> 6;
  // prologue: full tile 0 into buf0; WAITB(4) -> kh0 proven, kh1 in flight
  stageA(0, 0, 0);
  stageB(0, 0, 0);
  stageA(0, 1, 0);
  stageB(0, 1, 0);
  WAITB(4);

  int buf = 0;
  for (int t = 0; t < NT; ++t) {
    const int kkn = (t + 1 < NT) ? ((t + 1) << 6) : 0;  // clamp keeps counts uniform
    const int nb = buf ^ 65536;
    stageA(nb, 0, kkn);
    PHASE(buf, 0, 0, true);
    stageB(nb, 0, kkn);
    PHASE(buf, 1, 0, false);
    WAITB(8);                       // kh1(t) proven (r3 ledger)
    stageA(nb, 1, kkn);
    PHASE(buf, 0, 1, true);
    stageB(nb, 1, kkn);
    PHASE(buf, 1, 1, false);
    WAITB(4);                       // kh0(t+1) proven; in-flight = kh1(t+1)
    buf = nb;
  }
  asm volatile("s_waitcnt vmcnt(0)" ::: "memory");

  // epilogue: col = bn+wnCol+cf*32+l31 ; row = bm+wmRow+rf*32+(reg&3)+8*(reg>>2)+4*lh
  const int colbase = bn + wnCol + l31;
  const int rowbase0 = bm + wmRow + 4 * lh;
  #pragma unroll
  for (int rf = 0; rf < 4; rf++) {
    #pragma unroll
    for (int cf = 0; cf < 2; cf++) {
      const int col = colbase + cf * 32;
      #pragma unroll
      for (int reg = 0; reg < 16; reg++) {
        const int row = rowbase0 + rf * 32 + (reg & 3) + 8 * (reg >> 2);
        float v = acc[rf][cf][reg];
        if constexpr (EPI == EPI_QKV) {
          if (col < 2048) v = (v > 0.f) ? (v + 1.f) : __expf(v);  // phi = elu+1
          ((short*)outp)[(size_t)row * ldo + col] = f2b(v);
        } else if constexpr (EPI == EPI_RES) {
          ((short*)outp)[(size_t)row * ldo + col] =
              f2b(v + ((const float*)resid)[(size_t)row * ldo + col]);
        } else if constexpr (EPI == EPI_GELU) {
          v += bias[col];
          v = 0.5f * v * (1.f + erff(v * 0.70710678118654752f));
          ((short*)outp)[(size_t)row * ldo + col] = f2b(v);
        } else {  // EPI_FC2: bias + bf16 residual -> fp32 d_out
          v += bias[col] + b2f(((const short*)resid)[(size_t)row * ldo + col]);
          ((float*)outp)[(size_t)row * ldo + col] = v;
        }
      }
    }
  }
}

// ---------- kv partial reduce v3: 1024 blocks x 512 rows (kv_part 67->17MB) ----------
__global__ __launch_bounds__(256) void kv_reduce(
    const short* __restrict__ qkv, float* __restrict__ kv_part,
    float* __restrict__ ksum_part) {
  const int blk = blockIdx.x;  // 1024 = 64 bh * 16 chunks
  const int bh = blk >> 4, chunk = blk & 15;
  const int b = bh >> 4, h = bh & 15;
  const size_t rowbase = (size_t)b * 8192 + (size_t)chunk * 512;
  const int kcol = 1024 + h * 64, vcol = 2048 + h * 64;
  __shared__ float Klf[64][68];
  __shared__ float Vlf[64][68];
  const int tid = threadIdx.x;
  const int dk = tid >> 2, dq = tid & 3;
  float acc[16] = {};
  float ks = 0.f;
  for (int t = 0; t < 8; t++) {
    #pragma unroll
    for (int i = 0; i < 2; i++) {
      const int s = i * 256 + tid;
      const int r = s >> 3, seg = (s & 7) * 8;
      const size_t g = (rowbase + t * 64 + r) * 3072;
      const s16x8 k8 = *(const s16x8*)&qkv[g + kcol + seg];
      const s16x8 v8 = *(const s16x8*)&qkv[g + vcol + seg];
      float4 ka, kb, va, vb;
      ka.x = b2f(k8[0]); ka.y = b2f(k8[1]); ka.z = b2f(k8[2]); ka.w = b2f(k8[3]);
      kb.x = b2f(k8[4]); kb.y = b2f(k8[5]); kb.z = b2f(k8[6]); kb.w = b2f(k8[7]);
      va.x = b2f(v8[0]); va.y = b2f(v8[1]); va.z = b2f(v8[2]); va.w = b2f(v8[3]);
      vb.x = b2f(v8[4]); vb.y = b2f(v8[5]); vb.z = b2f(v8[6]); vb.w = b2f(v8[7]);
      *(float4*)&Klf[r][seg] = ka;
      *(float4*)&Klf[r][seg + 4] = kb;
      *(float4*)&Vlf[r][seg] = va;
      *(float4*)&Vlf[r][seg + 4] = vb;
    }
    __syncthreads();
    #pragma unroll 4
    for (int n = 0; n < 64; n++) {
      const float kval = Klf[n][dk];
      if (dq == 0) ks += kval;
      const float4 v0 = *(const float4*)&Vlf[n][dq * 16];
      const float4 v1 = *(const float4*)&Vlf[n][dq * 16 + 4];
      const float4 v2 = *(const float4*)&Vlf[n][dq * 16 + 8];
      const float4 v3 = *(const float4*)&Vlf[n][dq * 16 + 12];
      acc[0]  = fmaf(kval, v0.x, acc[0]);
      acc[1]  = fmaf(kval, v0.y, acc[1]);
      acc[2]  = fmaf(kval, v0.z, acc[2]);
      acc[3]  = fmaf(kval, v0.w, acc[3]);
      acc[4]  = fmaf(kval, v1.x, acc[4]);
      acc[5]  = fmaf(kval, v1.y, acc[5]);
      acc[6]  = fmaf(kval, v1.z, acc[6]);
      acc[7]  = fmaf(kval, v1.w, acc[7]);
      acc[8]  = fmaf(kval, v2.x, acc[8]);
      acc[9]  = fmaf(kval, v2.y, acc[9]);
      acc[10] = fmaf(kval, v2.z, acc[10]);
      acc[11] = fmaf(kval, v2.w, acc[11]);
      acc[12] = fmaf(kval, v3.x, acc[12]);
      acc[13] = fmaf(kval, v3.y, acc[13]);
      acc[14] = fmaf(kval, v3.z, acc[14]);
      acc[15] = fmaf(kval, v3.w, acc[15]);
    }
    __syncthreads();
  }
  float* dst = kv_part + (size_t)blk * 4096 + dk * 64 + dq * 16;
  #pragma unroll
  for (int j = 0; j < 16; j++) dst[j] = acc[j];
  if (dq == 0) ksum_part[(size_t)blk * 64 + dk] = ks;
}

// ---------- kv finalize: reduce 16 partials -> bf16 kv^T, pre-swizzled ----------
__global__ __launch_bounds__(256) void kv_finalize(
    const float* __restrict__ kv_part, const float* __restrict__ ksum_part,
    short* __restrict__ kvT_g, float* __restrict__ ksum_f) {
  const int bh = blockIdx.x >> 2, dg = blockIdx.x & 3;
  const int tid = threadIdx.x;
  const int e = tid & 63, j4 = tid >> 6;
  const int d0 = dg * 16 + j4 * 4;
  float a0 = 0.f, a1 = 0.f, a2 = 0.f, a3 = 0.f;
  const float* base = kv_part + (size_t)bh * 16 * 4096 + d0 * 64 + e;
  for (int c = 0; c < 16; c++) {
    const float* p = base + (size_t)c * 4096;
    a0 += p[0]; a1 += p[64]; a2 += p[128]; a3 += p[192];
  }
  s16x4 o; o.x = f2b(a0); o.y = f2b(a1); o.z = f2b(a2); o.w = f2b(a3);
  char* dstb = (char*)(kvT_g + (size_t)bh * 4096);
  *(s16x4*)(dstb + e * 128 + ((2 * d0) ^ ((e & 7) << 4))) = o;
  if (tid < 16) {
    const int d = dg * 16 + tid;
    float s = 0.f;
    for (int c = 0; c < 16; c++)
      s += ksum_part[((size_t)bh * 16 + c) * 64 + d];
    ksum_f[bh * 64 + d] = s;
  }
}

// ---------- attention apply via MFMA: ao = (Q @ kv) / (Q . ksum + eps) ----------
__global__ __launch_bounds__(256) void attn_apply_mfma(
    const short* __restrict__ qkv, const short* __restrict__ kvT_g,
    const float* __restrict__ ksum_f, short* __restrict__ ao) {
  __shared__ alignas(16) short kvs[4096];
  __shared__ float ksl[64];
  const int blk = blockIdx.x;
  const int bh = blk >> 5, rc = blk & 31;
  const int b = bh >> 4, h = bh & 15;
  const int tid = threadIdx.x, lane = tid & 63, w = tid >> 6;
  const int fr = lane & 15, fq = lane >> 4;

  GLD16(kvT_g + (size_t)bh * 4096 + tid * 8, (char*)kvs + tid * 16);
  GLD16(kvT_g + (size_t)bh * 4096 + (256 + tid) * 8, (char*)kvs + (256 + tid) * 16);
  if (tid < 64) ksl[tid] = ksum_f[bh * 64 + tid];
  __syncthreads();

  bf16x8 bkv[4][2], bns[2];
  #pragma unroll
  for (int n = 0; n < 4; n++) {
    #pragma unroll
    for (int c = 0; c < 2; c++) {
      const int e = n * 16 + fr;
      const int byteoff = e * 128 + ((c * 64 + fq * 16) ^ ((e & 7) << 4));
      bkv[n][c] = *(const bf16x8*)((const char*)kvs + byteoff);
    }
  }
  #pragma unroll
  for (int c = 0; c < 2; c++) {
    s16x8 ts = {0, 0, 0, 0, 0, 0, 0, 0};
    if (fr == 0) {
      #pragma unroll
      for (int j = 0; j < 8; j++) ts[j] = f2b(ksl[c * 32 + fq * 8 + j]);
    }
    bns[c] = asbf(ts);
  }

  f32x4 acc[4][4] = {};
  f32x4 nacc[4] = {};
  const size_t rowbase = (size_t)b * 8192 + (size_t)rc * 256 + w * 64;
  const int qcol = h * 64;
  #pragma unroll
  for (int m = 0; m < 4; m++) {
    const short* qrow = qkv + (rowbase + m * 16 + fr) * 3072 + qcol + fq * 8;
    const bf16x8 a0 = *(const bf16x8*)qrow;
    const bf16x8 a1 = *(const bf16x8*)(qrow + 32);
    #pragma unroll
    for (int n = 0; n < 4; n++) {
      acc[m][n] = __builtin_amdgcn_mfma_f32_16x16x32_bf16(a0, bkv[n][0], acc[m][n], 0, 0, 0);
      acc[m][n] = __builtin_amdgcn_mfma_f32_16x16x32_bf16(a1, bkv[n][1], acc[m][n], 0, 0, 0);
    }
    nacc[m] = __builtin_amdgcn_mfma_f32_16x16x32_bf16(a0, bns[0], nacc[m], 0, 0, 0);
    nacc[m] = __builtin_amdgcn_mfma_f32_16x16x32_bf16(a1, bns[1], nacc[m], 0, 0, 0);
  }

  #pragma unroll
  for (int m = 0; m < 4; m++) {
    #pragma unroll
    for (int r = 0; r < 4; r++) {
      const float nv = __shfl(nacc[m][r], lane & 48) + 1e-6f;
      const float rn = 1.f / nv;
      const size_t row = rowbase + m * 16 + fq * 4 + r;
      #pragma unroll
      for (int n = 0; n < 4; n++)
        ao[row * 1024 + qcol + n * 16 + fr] = f2b(acc[m][n][r] * rn);
    }
  }
}

// ---------- launcher ----------
extern "C" void kernel_launch(void* const* d_in, const int* in_sizes, int n_in,
                              void* d_out, int out_size, void* d_ws, size_t ws_size,
                              hipStream_t stream) {
  (void)in_sizes; (void)n_in; (void)out_size; (void)ws_size;
  const float* src   = (const float*)d_in[0];
  const float* ln1_w = (const float*)d_in[1];
  const float* ln1_b = (const float*)d_in[2];
  const float* wq    = (const float*)d_in[3];
  const float* wk    = (const float*)d_in[4];
  const float* wv    = (const float*)d_in[5];
  const float* wo    = (const float*)d_in[6];
  const float* ln2_w = (const float*)d_in[7];
  const float* ln2_b = (const float*)d_in[8];
  const float* fc1_w = (const float*)d_in[9];
  const float* fc1_b = (const float*)d_in[10];
  const float* fc2_w = (const float*)d_in[11];
  const float* fc2_b = (const float*)d_in[12];

  char* ws = (char*)d_ws;
  short* wqkvT     = (short*)(ws + 0);            // [3072][1024] bf16
  short* woT       = (short*)(ws + 6291456);      // [1024][1024]
  short* fc1T      = (short*)(ws + 8388608);      // [4096][1024]
  short* fc2T      = (short*)(ws + 16777216);     // [1024][4096]
  short* kvT_g     = (short*)(ws + 25165824);     // [64][4096] bf16 swizzled
  float* ksum_f    = (float*)(ws + 25690112);     // [64][64]
  float* kv_part   = (float*)(ws + 25706496);     // [1024][4096] fp32 (16.8MB)
  float* ksum_part = (float*)(ws + 42483712);     // [1024][64]
  short* hbuf      = (short*)(ws + 93863936);     // [32768][1024] bf16 (h / ao / h2)
  short* src2b     = (short*)(ws + 160972800);    // [32768][1024] bf16 (residual)
  short* qkv       = (short*)(ws + 295190528);    // [32768][3072] bf16
  short* a1c       = (short*)(ws + 295190528);    // [16384][4096] bf16 (aliases qkv)
  // high-water: 496,517,120 bytes (< 503,447,552 proven in round 1)

  const dim3 tb(256);
  const dim3 tb512(512);

  // weights -> bf16 transposed
  transpose_cvt<<<dim3(32, 32), tb, 0, stream>>>(wq, wqkvT, 1024, 1024);
  transpose_cvt<<<dim3(32, 32), tb, 0, stream>>>(wk, wqkvT + 1024 * 1024, 1024, 1024);
  transpose_cvt<<<dim3(32, 32), tb, 0, stream>>>(wv, wqkvT + 2048 * 1024, 1024, 1024);
  transpose_cvt<<<dim3(32, 32), tb, 0, stream>>>(wo, woT, 1024, 1024);
  transpose_cvt<<<dim3(128, 32), tb, 0, stream>>>(fc1_w, fc1T, 1024, 4096);
  transpose_cvt<<<dim3(32, 128), tb, 0, stream>>>(fc2_w, fc2T, 4096, 1024);

  // LN1: src (fp32) -> h (bf16)
  ln_kernel<<<32768, tb, 0, stream>>>(src, ln1_w, ln1_b, hbuf);

  // QKV projection + phi on Q,K   (M=32768, N=3072, K=1024; gx=128, gy=12)
  gemm256<EPI_QKV><<<dim3(1536), tb512, 0, stream>>>(
      hbuf, 1024, wqkvT, 1024, 3072, 128, nullptr, nullptr, qkv);

  // kv / ksum: partial reduce (v3) -> finalize (bf16, transposed, swizzled)
  kv_reduce<<<1024, tb, 0, stream>>>(qkv, kv_part, ksum_part);
  kv_finalize<<<256, tb, 0, stream>>>(kv_part, ksum_part, kvT_g, ksum_f);

  // attention apply via MFMA -> ao (hbuf)
  attn_apply_mfma<<<2048, tb, 0, stream>>>(qkv, kvT_g, ksum_f, hbuf);

  // O projection + residual(src fp32) -> src2b (bf16)  (gx=128, gy=4)
  gemm256<EPI_RES><<<dim3(512), tb512, 0, stream>>>(
      hbuf, 1024, woT, 1024, 1024, 128, nullptr, src, src2b);

  // LN2: src2b (bf16) -> h2 (bf16, reuse hbuf)
  ln_kernel_b<<<32768, tb, 0, stream>>>(src2b, ln2_w, ln2_b, hbuf);

  // MLP, 2 chunks of 16384 rows (a1c aliases dead qkv buffer)
  for (int c = 0; c < 2; c++) {
    const size_t mo = (size_t)c * 16384;
    // FC1: M=16384, N=4096, K=1024; gx=64, gy=16
    gemm256<EPI_GELU><<<dim3(1024), tb512, 0, stream>>>(
        hbuf + mo * 1024, 1024, fc1T, 1024, 4096, 64, fc1_b, nullptr, a1c);
    // FC2: M=16384, N=1024, K=4096; gx=64, gy=4 ; bf16 residual
    gemm256<EPI_FC2><<<dim3(256), tb512, 0, stream>>>(
        a1c, 4096, fc2T, 4096, 1024, 64, fc2_b, src2b + mo * 1024,
        (float*)d_out + mo * 1024);
  }
}

// Round 15
// 1154.287 us; speedup vs baseline: 1.0265x; 1.0265x over previous
//
#include <hip/hip_runtime.h>
#include <hip/hip_bf16.h>

// ---------- types ----------
typedef __attribute__((ext_vector_type(8))) short s16x8;
typedef __attribute__((ext_vector_type(4))) short s16x4;
typedef __attribute__((ext_vector_type(8))) __bf16 bf16x8;
typedef __attribute__((ext_vector_type(4))) float f32x4;
typedef __attribute__((ext_vector_type(16))) float f32x16;

__device__ __forceinline__ float b2f(short s) {
  union { float f; unsigned u; } x;
  x.u = ((unsigned)(unsigned short)s) << 16;
  return x.f;
}
__device__ __forceinline__ short f2b(float f) {
  union { float f; unsigned u; } x;
  x.f = f;
  unsigned r = x.u + 0x7fff + ((x.u >> 16) & 1);  // RNE
  return (short)(r >> 16);
}
__device__ __forceinline__ bf16x8 asbf(s16x8 v) {
  union { s16x8 s; bf16x8 b; } u; u.s = v; return u.b;
}

#define GLD16(g, l) __builtin_amdgcn_global_load_lds( \
    (const __attribute__((address_space(1))) void*)(g), \
    (__attribute__((address_space(3))) void*)(l), 16, 0, 0)

#define WAITB(N) do { \
  asm volatile("s_waitcnt vmcnt(" #N ")" ::: "memory"); \
  __builtin_amdgcn_s_barrier(); \
  asm volatile("" ::: "memory"); \
} while (0)

// ---------- weight transpose + fp32->bf16 : out[c][r] = in[r][c] ----------
__global__ __launch_bounds__(256) void transpose_cvt(
    const float* __restrict__ in, short* __restrict__ out, int R, int C) {
  __shared__ float tile[32][33];
  const int tx = threadIdx.x & 31, ty = threadIdx.x >> 5;  // 32x8
  const int c0 = blockIdx.x * 32, r0 = blockIdx.y * 32;
  #pragma unroll
  for (int i = 0; i < 32; i += 8)
    tile[ty + i][tx] = in[(size_t)(r0 + ty + i) * C + c0 + tx];
  __syncthreads();
  #pragma unroll
  for (int i = 0; i < 32; i += 8)
    out[(size_t)(c0 + ty + i) * R + r0 + tx] = f2b(tile[tx][ty + i]);
}

// ---------- layernorm: fp32 [rows][1024] -> bf16 ----------
__global__ __launch_bounds__(256) void ln_kernel(
    const float* __restrict__ x, const float* __restrict__ gw,
    const float* __restrict__ gb, short* __restrict__ out) {
  const int row = blockIdx.x;
  const int tid = threadIdx.x;
  const float4 v = ((const float4*)(x + (size_t)row * 1024))[tid];
  float s = v.x + v.y + v.z + v.w;
  float s2 = v.x * v.x + v.y * v.y + v.z * v.z + v.w * v.w;
  #pragma unroll
  for (int o = 32; o > 0; o >>= 1) {
    s += __shfl_xor(s, o);
    s2 += __shfl_xor(s2, o);
  }
  __shared__ float red[2][4];
  const int lane = tid & 63, wid = tid >> 6;
  if (lane == 0) { red[0][wid] = s; red[1][wid] = s2; }
  __syncthreads();
  s = red[0][0] + red[0][1] + red[0][2] + red[0][3];
  s2 = red[1][0] + red[1][1] + red[1][2] + red[1][3];
  const float mu = s * (1.f / 1024.f);
  const float rstd = rsqrtf(s2 * (1.f / 1024.f) - mu * mu + 1e-5f);
  const float4 wv4 = ((const float4*)gw)[tid];
  const float4 bv4 = ((const float4*)gb)[tid];
  s16x4 o4;
  o4.x = f2b((v.x - mu) * rstd * wv4.x + bv4.x);
  o4.y = f2b((v.y - mu) * rstd * wv4.y + bv4.y);
  o4.z = f2b((v.z - mu) * rstd * wv4.z + bv4.z);
  o4.w = f2b((v.w - mu) * rstd * wv4.w + bv4.w);
  *(s16x4*)(out + (size_t)row * 1024 + tid * 4) = o4;
}

// ---------- layernorm, bf16 input: [rows][1024] bf16 -> bf16 ----------
__global__ __launch_bounds__(256) void ln_kernel_b(
    const short* __restrict__ x, const float* __restrict__ gw,
    const float* __restrict__ gb, short* __restrict__ out) {
  const int row = blockIdx.x;
  const int tid = threadIdx.x;
  const s16x4 xv = *(const s16x4*)(x + (size_t)row * 1024 + tid * 4);
  float v0 = b2f(xv.x), v1 = b2f(xv.y), v2 = b2f(xv.z), v3 = b2f(xv.w);
  float s = v0 + v1 + v2 + v3;
  float s2 = v0 * v0 + v1 * v1 + v2 * v2 + v3 * v3;
  #pragma unroll
  for (int o = 32; o > 0; o >>= 1) {
    s += __shfl_xor(s, o);
    s2 += __shfl_xor(s2, o);
  }
  __shared__ float red[2][4];
  const int lane = tid & 63, wid = tid >> 6;
  if (lane == 0) { red[0][wid] = s; red[1][wid] = s2; }
  __syncthreads();
  s = red[0][0] + red[0][1] + red[0][2] + red[0][3];
  s2 = red[1][0] + red[1][1] + red[1][2] + red[1][3];
  const float mu = s * (1.f / 1024.f);
  const float rstd = rsqrtf(s2 * (1.f / 1024.f) - mu * mu + 1e-5f);
  const float4 wv4 = ((const float4*)gw)[tid];
  const float4 bv4 = ((const float4*)gb)[tid];
  s16x4 o4;
  o4.x = f2b((v0 - mu) * rstd * wv4.x + bv4.x);
  o4.y = f2b((v1 - mu) * rstd * wv4.y + bv4.y);
  o4.z = f2b((v2 - mu) * rstd * wv4.z + bv4.z);
  o4.w = f2b((v3 - mu) * rstd * wv4.w + bv4.w);
  *(s16x4*)(out + (size_t)row * 1024 + tid * 4) = o4;
}

// ---------- 256x256 bf16 MFMA GEMM: 32x32x16 MFMA, bit4-fixed swizzle ----------
// r15 fix (r14 post-mortem): 32x32 read paired lanes l31/l31+16 at same slot
// (same (row>>1)&7, row&1, q) -> 4-way bank alias (1.9e7 conflicts, +22us).
// New slot folds row bit4: s = ((row&1)<<2|q) ^ ((row>>1)&7) ^ ((row>>4)&1);
// write side s0 = (tid&7) ^ (sg&7) ^ ((sg>>3)&1) (both-sides, rule #21).
// Consistency: 2nd GLD16 (row+128, g+64) flips neither (row>>1)&7, (row>>4)&1
// relation nor (g>>3)&1 parity -> same s0 formula serves both sub-loads.
// Within any 16-lane granule bit4 is constant -> 2-way (free) as in 16x16.

enum { EPI_QKV = 0, EPI_RES = 1, EPI_GELU = 2, EPI_FC2 = 3 };

#define PHASE(BUFB, MH, KS, LOADB) do { \
    const int ab = (BUFB) + (KS) * 16384; \
    const int bb = (BUFB) + 32768 + (KS) * 16384; \
    if (LOADB) { \
      _Pragma("unroll") \
      for (int cf = 0; cf < 2; cf++) \
        _Pragma("unroll") \
        for (int w = 0; w < 2; w++) { \
          const int row = wnCol + cf * 32 + l31; \
          const int g = row >> 1; \
          const int q = 2 * w + lh; \
          const int s = ((((row & 1) << 2) | q) ^ (g & 7)) ^ ((row >> 4) & 1); \
          bfvw[cf][w] = *(const bf16x8*)(ldsc + bb + g * 128 + s * 16); \
        } \
    } \
    bf16x8 af[2][2]; \
    _Pragma("unroll") \
    for (int rf = 0; rf < 2; rf++) \
      _Pragma("unroll") \
      for (int w = 0; w < 2; w++) { \
        const int row = wmRow + ((MH) * 2 + rf) * 32 + l31; \
        const int g = row >> 1; \
        const int q = 2 * w + lh; \
        const int s = ((((row & 1) << 2) | q) ^ (g & 7)) ^ ((row >> 4) & 1); \
        af[rf][w] = *(const bf16x8*)(ldsc + ab + g * 128 + s * 16); \
      } \
    __builtin_amdgcn_s_setprio(1); \
    _Pragma("unroll") \
    for (int w = 0; w < 2; w++) \
      _Pragma("unroll") \
      for (int rf = 0; rf < 2; rf++) \
        _Pragma("unroll") \
        for (int cf = 0; cf < 2; cf++) \
          acc[(MH) * 2 + rf][cf] = __builtin_amdgcn_mfma_f32_32x32x16_bf16( \
              af[rf][w], bfvw[cf][w], acc[(MH) * 2 + rf][cf], 0, 0, 0); \
    __builtin_amdgcn_s_setprio(0); \
  } while (0)

template <int EPI>
__global__ __launch_bounds__(512, 2) void gemm256(
    const short* __restrict__ A, int lda,
    const short* __restrict__ Bt, int K, int ldo, int gx,
    const float* __restrict__ bias,
    const void* __restrict__ resid,
    void* __restrict__ outp) {
  __shared__ alignas(16) short lds[65536];  // 128 KiB
  const int tid = threadIdx.x;
  const int lane = tid & 63, wave = tid >> 6;
  // T1: bijective XCD swizzle (grid % 8 == 0 for all launches)
  const int cpx = (int)gridDim.x >> 3;
  const int bid = ((int)blockIdx.x & 7) * cpx + ((int)blockIdx.x >> 3);
  // L2 super-tile mapping: 32-block groups of 8bm x 4bn
  const int sgx = gx >> 3;
  const int grp = bid >> 5;
  const int sm = grp % sgx, sn = grp / sgx;
  const int bm = (sm * 8 + (bid & 7)) * 256;
  const int bn = (sn * 4 + ((bid & 31) >> 3)) * 256;
  const int wmRow = (wave >> 2) * 128;
  const int wnCol = (wave & 3) * 64;
  const int l31 = lane & 31, lh = lane >> 5;

  // staging constants: inverse-swizzled global source (incl. bit4 term),
  // linear LDS dest
  const int sg = tid >> 3;
  const int s0 = (tid & 7) ^ (sg & 7) ^ ((sg >> 3) & 1);
  const int srow = 2 * sg + (s0 >> 2);   // load 0 row; load 1 adds 128
  const int scol = (s0 & 3) * 8;
  const int sdst = tid * 16;

  const char* ldsc = (const char*)lds;
  char* ldsw = (char*)lds;

  f32x16 acc[4][2] = {};
  bf16x8 bfvw[2][2];

  auto stageA = [&](int bufb, int kh, int kk) {
    const short* g = A + (size_t)(bm + srow) * lda + kk + kh * 32 + scol;
    char* l = ldsw + bufb + kh * 16384 + sdst;
    GLD16(g, l);
    GLD16(g + (size_t)128 * lda, l + 8192);
  };
  auto stageB = [&](int bufb, int kh, int kk) {
    const short* g = Bt + (size_t)(bn + srow) * K + kk + kh * 32 + scol;
    char* l = ldsw + bufb + 32768 + kh * 16384 + sdst;
    GLD16(g, l);
    GLD16(g + (size_t)128 * K, l + 8192);
  };

  const int NT = K >> 6;
  // prologue: full tile 0 into buf0; WAITB(4) -> kh0 proven, kh1 in flight
  stageA(0, 0, 0);
  stageB(0, 0, 0);
  stageA(0, 1, 0);
  stageB(0, 1, 0);
  WAITB(4);

  int buf = 0;
  for (int t = 0; t < NT; ++t) {
    const int kkn = (t + 1 < NT) ? ((t + 1) << 6) : 0;  // clamp keeps counts uniform
    const int nb = buf ^ 65536;
    stageA(nb, 0, kkn);
    PHASE(buf, 0, 0, true);
    stageB(nb, 0, kkn);
    PHASE(buf, 1, 0, false);
    WAITB(8);                       // kh1(t) proven (r3 ledger)
    stageA(nb, 1, kkn);
    PHASE(buf, 0, 1, true);
    stageB(nb, 1, kkn);
    PHASE(buf, 1, 1, false);
    WAITB(4);                       // kh0(t+1) proven; in-flight = kh1(t+1)
    buf = nb;
  }
  asm volatile("s_waitcnt vmcnt(0)" ::: "memory");

  // epilogue: col = bn+wnCol+cf*32+l31 ; row = bm+wmRow+rf*32+(reg&3)+8*(reg>>2)+4*lh
  const int colbase = bn + wnCol + l31;
  const int rowbase0 = bm + wmRow + 4 * lh;
  #pragma unroll
  for (int rf = 0; rf < 4; rf++) {
    #pragma unroll
    for (int cf = 0; cf < 2; cf++) {
      const int col = colbase + cf * 32;
      #pragma unroll
      for (int reg = 0; reg < 16; reg++) {
        const int row = rowbase0 + rf * 32 + (reg & 3) + 8 * (reg >> 2);
        float v = acc[rf][cf][reg];
        if constexpr (EPI == EPI_QKV) {
          if (col < 2048) v = (v > 0.f) ? (v + 1.f) : __expf(v);  // phi = elu+1
          ((short*)outp)[(size_t)row * ldo + col] = f2b(v);
        } else if constexpr (EPI == EPI_RES) {
          ((short*)outp)[(size_t)row * ldo + col] =
              f2b(v + ((const float*)resid)[(size_t)row * ldo + col]);
        } else if constexpr (EPI == EPI_GELU) {
          v += bias[col];
          v = 0.5f * v * (1.f + erff(v * 0.70710678118654752f));
          ((short*)outp)[(size_t)row * ldo + col] = f2b(v);
        } else {  // EPI_FC2: bias + bf16 residual -> fp32 d_out
          v += bias[col] + b2f(((const short*)resid)[(size_t)row * ldo + col]);
          ((float*)outp)[(size_t)row * ldo + col] = v;
        }
      }
    }
  }
}

// ---------- kv partial reduce v3: 1024 blocks x 512 rows ----------
__global__ __launch_bounds__(256) void kv_reduce(
    const short* __restrict__ qkv, float* __restrict__ kv_part,
    float* __restrict__ ksum_part) {
  const int blk = blockIdx.x;  // 1024 = 64 bh * 16 chunks
  const int bh = blk >> 4, chunk = blk & 15;
  const int b = bh >> 4, h = bh & 15;
  const size_t rowbase = (size_t)b * 8192 + (size_t)chunk * 512;
  const int kcol = 1024 + h * 64, vcol = 2048 + h * 64;
  __shared__ float Klf[64][68];
  __shared__ float Vlf[64][68];
  const int tid = threadIdx.x;
  const int dk = tid >> 2, dq = tid & 3;
  float acc[16] = {};
  float ks = 0.f;
  for (int t = 0; t < 8; t++) {
    #pragma unroll
    for (int i = 0; i < 2; i++) {
      const int s = i * 256 + tid;
      const int r = s >> 3, seg = (s & 7) * 8;
      const size_t g = (rowbase + t * 64 + r) * 3072;
      const s16x8 k8 = *(const s16x8*)&qkv[g + kcol + seg];
      const s16x8 v8 = *(const s16x8*)&qkv[g + vcol + seg];
      float4 ka, kb, va, vb;
      ka.x = b2f(k8[0]); ka.y = b2f(k8[1]); ka.z = b2f(k8[2]); ka.w = b2f(k8[3]);
      kb.x = b2f(k8[4]); kb.y = b2f(k8[5]); kb.z = b2f(k8[6]); kb.w = b2f(k8[7]);
      va.x = b2f(v8[0]); va.y = b2f(v8[1]); va.z = b2f(v8[2]); va.w = b2f(v8[3]);
      vb.x = b2f(v8[4]); vb.y = b2f(v8[5]); vb.z = b2f(v8[6]); vb.w = b2f(v8[7]);
      *(float4*)&Klf[r][seg] = ka;
      *(float4*)&Klf[r][seg + 4] = kb;
      *(float4*)&Vlf[r][seg] = va;
      *(float4*)&Vlf[r][seg + 4] = vb;
    }
    __syncthreads();
    #pragma unroll 4
    for (int n = 0; n < 64; n++) {
      const float kval = Klf[n][dk];
      if (dq == 0) ks += kval;
      const float4 v0 = *(const float4*)&Vlf[n][dq * 16];
      const float4 v1 = *(const float4*)&Vlf[n][dq * 16 + 4];
      const float4 v2 = *(const float4*)&Vlf[n][dq * 16 + 8];
      const float4 v3 = *(const float4*)&Vlf[n][dq * 16 + 12];
      acc[0]  = fmaf(kval, v0.x, acc[0]);
      acc[1]  = fmaf(kval, v0.y, acc[1]);
      acc[2]  = fmaf(kval, v0.z, acc[2]);
      acc[3]  = fmaf(kval, v0.w, acc[3]);
      acc[4]  = fmaf(kval, v1.x, acc[4]);
      acc[5]  = fmaf(kval, v1.y, acc[5]);
      acc[6]  = fmaf(kval, v1.z, acc[6]);
      acc[7]  = fmaf(kval, v1.w, acc[7]);
      acc[8]  = fmaf(kval, v2.x, acc[8]);
      acc[9]  = fmaf(kval, v2.y, acc[9]);
      acc[10] = fmaf(kval, v2.z, acc[10]);
      acc[11] = fmaf(kval, v2.w, acc[11]);
      acc[12] = fmaf(kval, v3.x, acc[12]);
      acc[13] = fmaf(kval, v3.y, acc[13]);
      acc[14] = fmaf(kval, v3.z, acc[14]);
      acc[15] = fmaf(kval, v3.w, acc[15]);
    }
    __syncthreads();
  }
  float* dst = kv_part + (size_t)blk * 4096 + dk * 64 + dq * 16;
  #pragma unroll
  for (int j = 0; j < 16; j++) dst[j] = acc[j];
  if (dq == 0) ksum_part[(size_t)blk * 64 + dk] = ks;
}

// ---------- kv finalize: reduce 16 partials -> bf16 kv^T, pre-swizzled ----------
__global__ __launch_bounds__(256) void kv_finalize(
    const float* __restrict__ kv_part, const float* __restrict__ ksum_part,
    short* __restrict__ kvT_g, float* __restrict__ ksum_f) {
  const int bh = blockIdx.x >> 2, dg = blockIdx.x & 3;
  const int tid = threadIdx.x;
  const int e = tid & 63, j4 = tid >> 6;
  const int d0 = dg * 16 + j4 * 4;
  float a0 = 0.f, a1 = 0.f, a2 = 0.f, a3 = 0.f;
  const float* base = kv_part + (size_t)bh * 16 * 4096 + d0 * 64 + e;
  for (int c = 0; c < 16; c++) {
    const float* p = base + (size_t)c * 4096;
    a0 += p[0]; a1 += p[64]; a2 += p[128]; a3 += p[192];
  }
  s16x4 o; o.x = f2b(a0); o.y = f2b(a1); o.z = f2b(a2); o.w = f2b(a3);
  char* dstb = (char*)(kvT_g + (size_t)bh * 4096);
  *(s16x4*)(dstb + e * 128 + ((2 * d0) ^ ((e & 7) << 4))) = o;
  if (tid < 16) {
    const int d = dg * 16 + tid;
    float s = 0.f;
    for (int c = 0; c < 16; c++)
      s += ksum_part[((size_t)bh * 16 + c) * 64 + d];
    ksum_f[bh * 64 + d] = s;
  }
}

// ---------- attention apply via MFMA: ao = (Q @ kv) / (Q . ksum + eps) ----------
__global__ __launch_bounds__(256) void attn_apply_mfma(
    const short* __restrict__ qkv, const short* __restrict__ kvT_g,
    const float* __restrict__ ksum_f, short* __restrict__ ao) {
  __shared__ alignas(16) short kvs[4096];
  __shared__ float ksl[64];
  const int blk = blockIdx.x;
  const int bh = blk >> 5, rc = blk & 31;
  const int b = bh >> 4, h = bh & 15;
  const int tid = threadIdx.x, lane = tid & 63, w = tid >> 6;
  const int fr = lane & 15, fq = lane >> 4;

  GLD16(kvT_g + (size_t)bh * 4096 + tid * 8, (char*)kvs + tid * 16);
  GLD16(kvT_g + (size_t)bh * 4096 + (256 + tid) * 8, (char*)kvs + (256 + tid) * 16);
  if (tid < 64) ksl[tid] = ksum_f[bh * 64 + tid];
  __syncthreads();

  bf16x8 bkv[4][2], bns[2];
  #pragma unroll
  for (int n = 0; n < 4; n++) {
    #pragma unroll
    for (int c = 0; c < 2; c++) {
      const int e = n * 16 + fr;
      const int byteoff = e * 128 + ((c * 64 + fq * 16) ^ ((e & 7) << 4));
      bkv[n][c] = *(const bf16x8*)((const char*)kvs + byteoff);
    }
  }
  #pragma unroll
  for (int c = 0; c < 2; c++) {
    s16x8 ts = {0, 0, 0, 0, 0, 0, 0, 0};
    if (fr == 0) {
      #pragma unroll
      for (int j = 0; j < 8; j++) ts[j] = f2b(ksl[c * 32 + fq * 8 + j]);
    }
    bns[c] = asbf(ts);
  }

  f32x4 acc[4][4] = {};
  f32x4 nacc[4] = {};
  const size_t rowbase = (size_t)b * 8192 + (size_t)rc * 256 + w * 64;
  const int qcol = h * 64;
  #pragma unroll
  for (int m = 0; m < 4; m++) {
    const short* qrow = qkv + (rowbase + m * 16 + fr) * 3072 + qcol + fq * 8;
    const bf16x8 a0 = *(const bf16x8*)qrow;
    const bf16x8 a1 = *(const bf16x8*)(qrow + 32);
    #pragma unroll
    for (int n = 0; n < 4; n++) {
      acc[m][n] = __builtin_amdgcn_mfma_f32_16x16x32_bf16(a0, bkv[n][0], acc[m][n], 0, 0, 0);
      acc[m][n] = __builtin_amdgcn_mfma_f32_16x16x32_bf16(a1, bkv[n][1], acc[m][n], 0, 0, 0);
    }
    nacc[m] = __builtin_amdgcn_mfma_f32_16x16x32_bf16(a0, bns[0], nacc[m], 0, 0, 0);
    nacc[m] = __builtin_amdgcn_mfma_f32_16x16x32_bf16(a1, bns[1], nacc[m], 0, 0, 0);
  }

  #pragma unroll
  for (int m = 0; m < 4; m++) {
    #pragma unroll
    for (int r = 0; r < 4; r++) {
      const float nv = __shfl(nacc[m][r], lane & 48) + 1e-6f;
      const float rn = 1.f / nv;
      const size_t row = rowbase + m * 16 + fq * 4 + r;
      #pragma unroll
      for (int n = 0; n < 4; n++)
        ao[row * 1024 + qcol + n * 16 + fr] = f2b(acc[m][n][r] * rn);
    }
  }
}

// ---------- launcher ----------
extern "C" void kernel_launch(void* const* d_in, const int* in_sizes, int n_in,
                              void* d_out, int out_size, void* d_ws, size_t ws_size,
                              hipStream_t stream) {
  (void)in_sizes; (void)n_in; (void)out_size; (void)ws_size;
  const float* src   = (const float*)d_in[0];
  const float* ln1_w = (const float*)d_in[1];
  const float* ln1_b = (const float*)d_in[2];
  const float* wq    = (const float*)d_in[3];
  const float* wk    = (const float*)d_in[4];
  const float* wv    = (const float*)d_in[5];
  const float* wo    = (const float*)d_in[6];
  const float* ln2_w = (const float*)d_in[7];
  const float* ln2_b = (const float*)d_in[8];
  const float* fc1_w = (const float*)d_in[9];
  const float* fc1_b = (const float*)d_in[10];
  const float* fc2_w = (const float*)d_in[11];
  const float* fc2_b = (const float*)d_in[12];

  char* ws = (char*)d_ws;
  short* wqkvT     = (short*)(ws + 0);            // [3072][1024] bf16
  short* woT       = (short*)(ws + 6291456);      // [1024][1024]
  short* fc1T      = (short*)(ws + 8388608);      // [4096][1024]
  short* fc2T      = (short*)(ws + 16777216);     // [1024][4096]
  short* kvT_g     = (short*)(ws + 25165824);     // [64][4096] bf16 swizzled
  float* ksum_f    = (float*)(ws + 25690112);     // [64][64]
  float* kv_part   = (float*)(ws + 25706496);     // [1024][4096] fp32 (16.8MB)
  float* ksum_part = (float*)(ws + 42483712);     // [1024][64]
  short* hbuf      = (short*)(ws + 93863936);     // [32768][1024] bf16 (h / ao / h2)
  short* src2b     = (short*)(ws + 160972800);    // [32768][1024] bf16 (residual)
  short* qkv       = (short*)(ws + 295190528);    // [32768][3072] bf16
  short* a1c       = (short*)(ws + 295190528);    // [16384][4096] bf16 (aliases qkv)
  // high-water: 496,517,120 bytes (< 503,447,552 proven in round 1)

  const dim3 tb(256);
  const dim3 tb512(512);

  // weights -> bf16 transposed
  transpose_cvt<<<dim3(32, 32), tb, 0, stream>>>(wq, wqkvT, 1024, 1024);
  transpose_cvt<<<dim3(32, 32), tb, 0, stream>>>(wk, wqkvT + 1024 * 1024, 1024, 1024);
  transpose_cvt<<<dim3(32, 32), tb, 0, stream>>>(wv, wqkvT + 2048 * 1024, 1024, 1024);
  transpose_cvt<<<dim3(32, 32), tb, 0, stream>>>(wo, woT, 1024, 1024);
  transpose_cvt<<<dim3(128, 32), tb, 0, stream>>>(fc1_w, fc1T, 1024, 4096);
  transpose_cvt<<<dim3(32, 128), tb, 0, stream>>>(fc2_w, fc2T, 4096, 1024);

  // LN1: src (fp32) -> h (bf16)
  ln_kernel<<<32768, tb, 0, stream>>>(src, ln1_w, ln1_b, hbuf);

  // QKV projection + phi on Q,K   (M=32768, N=3072, K=1024; gx=128, gy=12)
  gemm256<EPI_QKV><<<dim3(1536), tb512, 0, stream>>>(
      hbuf, 1024, wqkvT, 1024, 3072, 128, nullptr, nullptr, qkv);

  // kv / ksum: partial reduce (v3) -> finalize (bf16, transposed, swizzled)
  kv_reduce<<<1024, tb, 0, stream>>>(qkv, kv_part, ksum_part);
  kv_finalize<<<256, tb, 0, stream>>>(kv_part, ksum_part, kvT_g, ksum_f);

  // attention apply via MFMA -> ao (hbuf)
  attn_apply_mfma<<<2048, tb, 0, stream>>>(qkv, kvT_g, ksum_f, hbuf);

  // O projection + residual(src fp32) -> src2b (bf16)  (gx=128, gy=4)
  gemm256<EPI_RES><<<dim3(512), tb512, 0, stream>>>(
      hbuf, 1024, woT, 1024, 1024, 128, nullptr, src, src2b);

  // LN2: src2b (bf16) -> h2 (bf16, reuse hbuf)
  ln_kernel_b<<<32768, tb, 0, stream>>>(src2b, ln2_w, ln2_b, hbuf);

  // MLP, 2 chunks of 16384 rows (a1c aliases dead qkv buffer)
  for (int c = 0; c < 2; c++) {
    const size_t mo = (size_t)c * 16384;
    // FC1: M=16384, N=4096, K=1024; gx=64, gy=16
    gemm256<EPI_GELU><<<dim3(1024), tb512, 0, stream>>>(
        hbuf + mo * 1024, 1024, fc1T, 1024, 4096, 64, fc1_b, nullptr, a1c);
    // FC2: M=16384, N=1024, K=4096; gx=64, gy=4 ; bf16 residual
    gemm256<EPI_FC2><<<dim3(256), tb512, 0, stream>>>(
        a1c, 4096, fc2T, 4096, 1024, 64, fc2_b, src2b + mo * 1024,
        (float*)d_out + mo * 1024);
  }
}

// Round 16
// 1124.024 us; speedup vs baseline: 1.0542x; 1.0269x over previous
//
#include <hip/hip_runtime.h>
#include <hip/hip_bf16.h>

// ---------- types ----------
typedef __attribute__((ext_vector_type(8))) short s16x8;
typedef __attribute__((ext_vector_type(4))) short s16x4;
typedef __attribute__((ext_vector_type(8))) __bf16 bf16x8;
typedef __attribute__((ext_vector_type(4))) float f32x4;

__device__ __forceinline__ float b2f(short s) {
  union { float f; unsigned u; } x;
  x.u = ((unsigned)(unsigned short)s) << 16;
  return x.f;
}
__device__ __forceinline__ short f2b(float f) {
  union { float f; unsigned u; } x;
  x.f = f;
  unsigned r = x.u + 0x7fff + ((x.u >> 16) & 1);  // RNE
  return (short)(r >> 16);
}
__device__ __forceinline__ bf16x8 asbf(s16x8 v) {
  union { s16x8 s; bf16x8 b; } u; u.s = v; return u.b;
}

#define GLD16(g, l) __builtin_amdgcn_global_load_lds( \
    (const __attribute__((address_space(1))) void*)(g), \
    (__attribute__((address_space(3))) void*)(l), 16, 0, 0)

#define WAITB(N) do { \
  asm volatile("s_waitcnt vmcnt(" #N ")" ::: "memory"); \
  __builtin_amdgcn_s_barrier(); \
  asm volatile("" ::: "memory"); \
} while (0)

// ---------- weight transpose + fp32->bf16 : out[c][r] = in[r][c] ----------
__global__ __launch_bounds__(256) void transpose_cvt(
    const float* __restrict__ in, short* __restrict__ out, int R, int C) {
  __shared__ float tile[32][33];
  const int tx = threadIdx.x & 31, ty = threadIdx.x >> 5;  // 32x8
  const int c0 = blockIdx.x * 32, r0 = blockIdx.y * 32;
  #pragma unroll
  for (int i = 0; i < 32; i += 8)
    tile[ty + i][tx] = in[(size_t)(r0 + ty + i) * C + c0 + tx];
  __syncthreads();
  #pragma unroll
  for (int i = 0; i < 32; i += 8)
    out[(size_t)(c0 + ty + i) * R + r0 + tx] = f2b(tile[tx][ty + i]);
}

// ---------- layernorm: fp32 [rows][1024] -> bf16 ----------
__global__ __launch_bounds__(256) void ln_kernel(
    const float* __restrict__ x, const float* __restrict__ gw,
    const float* __restrict__ gb, short* __restrict__ out) {
  const int row = blockIdx.x;
  const int tid = threadIdx.x;
  const float4 v = ((const float4*)(x + (size_t)row * 1024))[tid];
  float s = v.x + v.y + v.z + v.w;
  float s2 = v.x * v.x + v.y * v.y + v.z * v.z + v.w * v.w;
  #pragma unroll
  for (int o = 32; o > 0; o >>= 1) {
    s += __shfl_xor(s, o);
    s2 += __shfl_xor(s2, o);
  }
  __shared__ float red[2][4];
  const int lane = tid & 63, wid = tid >> 6;
  if (lane == 0) { red[0][wid] = s; red[1][wid] = s2; }
  __syncthreads();
  s = red[0][0] + red[0][1] + red[0][2] + red[0][3];
  s2 = red[1][0] + red[1][1] + red[1][2] + red[1][3];
  const float mu = s * (1.f / 1024.f);
  const float rstd = rsqrtf(s2 * (1.f / 1024.f) - mu * mu + 1e-5f);
  const float4 wv4 = ((const float4*)gw)[tid];
  const float4 bv4 = ((const float4*)gb)[tid];
  s16x4 o4;
  o4.x = f2b((v.x - mu) * rstd * wv4.x + bv4.x);
  o4.y = f2b((v.y - mu) * rstd * wv4.y + bv4.y);
  o4.z = f2b((v.z - mu) * rstd * wv4.z + bv4.z);
  o4.w = f2b((v.w - mu) * rstd * wv4.w + bv4.w);
  *(s16x4*)(out + (size_t)row * 1024 + tid * 4) = o4;
}

// ---------- layernorm, bf16 input: [rows][1024] bf16 -> bf16 ----------
__global__ __launch_bounds__(256) void ln_kernel_b(
    const short* __restrict__ x, const float* __restrict__ gw,
    const float* __restrict__ gb, short* __restrict__ out) {
  const int row = blockIdx.x;
  const int tid = threadIdx.x;
  const s16x4 xv = *(const s16x4*)(x + (size_t)row * 1024 + tid * 4);
  float v0 = b2f(xv.x), v1 = b2f(xv.y), v2 = b2f(xv.z), v3 = b2f(xv.w);
  float s = v0 + v1 + v2 + v3;
  float s2 = v0 * v0 + v1 * v1 + v2 * v2 + v3 * v3;
  #pragma unroll
  for (int o = 32; o > 0; o >>= 1) {
    s += __shfl_xor(s, o);
    s2 += __shfl_xor(s2, o);
  }
  __shared__ float red[2][4];
  const int lane = tid & 63, wid = tid >> 6;
  if (lane == 0) { red[0][wid] = s; red[1][wid] = s2; }
  __syncthreads();
  s = red[0][0] + red[0][1] + red[0][2] + red[0][3];
  s2 = red[1][0] + red[1][1] + red[1][2] + red[1][3];
  const float mu = s * (1.f / 1024.f);
  const float rstd = rsqrtf(s2 * (1.f / 1024.f) - mu * mu + 1e-5f);
  const float4 wv4 = ((const float4*)gw)[tid];
  const float4 bv4 = ((const float4*)gb)[tid];
  s16x4 o4;
  o4.x = f2b((v0 - mu) * rstd * wv4.x + bv4.x);
  o4.y = f2b((v1 - mu) * rstd * wv4.y + bv4.y);
  o4.z = f2b((v2 - mu) * rstd * wv4.z + bv4.z);
  o4.w = f2b((v3 - mu) * rstd * wv4.w + bv4.w);
  *(s16x4*)(out + (size_t)row * 1024 + tid * 4) = o4;
}

// ---------- 256x256 bf16 MFMA GEMM (r13-proven: 16x16x32, super-tile map) ----------
// r16: revert of the 32x32 experiment (r14/r15). With 0 conflicts and equal
// traffic, 32x32 measured SLOWER than 16x16 (222.6 vs 215.2us) — at 43%
// MfmaUtil the kernel is not pipe-bound, so the rate advantage is unbuyable;
// longer MFMA latency + f32x16 epilogue cost ~3%. This is r13's GEMM
// byte-for-byte (best-known across 15 rounds of variants).

enum { EPI_QKV = 0, EPI_RES = 1, EPI_GELU = 2, EPI_FC2 = 3 };

#define PHASE(BUFB, MH, KS, LOADB) do { \
    const int ab = (BUFB) + (KS) * 16384; \
    const int bb = (BUFB) + 32768 + (KS) * 16384; \
    if (LOADB) { \
      _Pragma("unroll") \
      for (int n = 0; n < 4; n++) { \
        const int row = wnCol + n * 16 + fr; \
        const int g = row >> 1; \
        const int s = (((row & 1) << 2) | fq) ^ (g & 7); \
        bfv[n] = *(const bf16x8*)(ldsc + bb + g * 128 + s * 16); \
      } \
    } \
    bf16x8 af[4]; \
    _Pragma("unroll") \
    for (int mm = 0; mm < 4; mm++) { \
      const int row = wmRow + (MH) * 64 + mm * 16 + fr; \
      const int g = row >> 1; \
      const int s = (((row & 1) << 2) | fq) ^ (g & 7); \
      af[mm] = *(const bf16x8*)(ldsc + ab + g * 128 + s * 16); \
    } \
    __builtin_amdgcn_s_setprio(1); \
    _Pragma("unroll") \
    for (int mm = 0; mm < 4; mm++) \
      _Pragma("unroll") \
      for (int n = 0; n < 4; n++) \
        acc[(MH) * 4 + mm][n] = __builtin_amdgcn_mfma_f32_16x16x32_bf16( \
            af[mm], bfv[n], acc[(MH) * 4 + mm][n], 0, 0, 0); \
    __builtin_amdgcn_s_setprio(0); \
  } while (0)

template <int EPI>
__global__ __launch_bounds__(512, 2) void gemm256(
    const short* __restrict__ A, int lda,
    const short* __restrict__ Bt, int K, int ldo, int gx,
    const float* __restrict__ bias,
    const void* __restrict__ resid,
    void* __restrict__ outp) {
  __shared__ alignas(16) short lds[65536];  // 128 KiB
  const int tid = threadIdx.x;
  const int lane = tid & 63, wave = tid >> 6;
  // T1: bijective XCD swizzle (grid % 8 == 0 for all launches)
  const int cpx = (int)gridDim.x >> 3;
  const int bid = ((int)blockIdx.x & 7) * cpx + ((int)blockIdx.x >> 3);
  // L2 super-tile mapping: 32-block groups of 8bm x 4bn
  const int sgx = gx >> 3;
  const int grp = bid >> 5;
  const int sm = grp % sgx, sn = grp / sgx;
  const int bm = (sm * 8 + (bid & 7)) * 256;
  const int bn = (sn * 4 + ((bid & 31) >> 3)) * 256;
  const int wmRow = (wave >> 2) * 128;
  const int wnCol = (wave & 3) * 64;
  const int fr = lane & 15, fq = lane >> 4;

  // staging constants: inverse-swizzled global source, linear LDS dest
  const int sg = tid >> 3;
  const int s0 = (tid & 7) ^ (sg & 7);
  const int srow = 2 * sg + (s0 >> 2);   // load 0 row; load 1 adds 128
  const int scol = (s0 & 3) * 8;
  const int sdst = tid * 16;

  const char* ldsc = (const char*)lds;
  char* ldsw = (char*)lds;

  f32x4 acc[8][4] = {};
  bf16x8 bfv[4];

  auto stageA = [&](int bufb, int kh, int kk) {
    const short* g = A + (size_t)(bm + srow) * lda + kk + kh * 32 + scol;
    char* l = ldsw + bufb + kh * 16384 + sdst;
    GLD16(g, l);
    GLD16(g + (size_t)128 * lda, l + 8192);
  };
  auto stageB = [&](int bufb, int kh, int kk) {
    const short* g = Bt + (size_t)(bn + srow) * K + kk + kh * 32 + scol;
    char* l = ldsw + bufb + 32768 + kh * 16384 + sdst;
    GLD16(g, l);
    GLD16(g + (size_t)128 * K, l + 8192);
  };

  const int NT = K >> 6;
  // prologue: full tile 0 into buf0; WAITB(4) -> kh0 proven, kh1 in flight
  stageA(0, 0, 0);
  stageB(0, 0, 0);
  stageA(0, 1, 0);
  stageB(0, 1, 0);
  WAITB(4);

  int buf = 0;
  for (int t = 0; t < NT; ++t) {
    const int kkn = (t + 1 < NT) ? ((t + 1) << 6) : 0;  // clamp keeps counts uniform
    const int nb = buf ^ 65536;
    stageA(nb, 0, kkn);
    PHASE(buf, 0, 0, true);
    stageB(nb, 0, kkn);
    PHASE(buf, 1, 0, false);
    WAITB(8);                       // kh1(t) proven (r3 ledger)
    stageA(nb, 1, kkn);
    PHASE(buf, 0, 1, true);
    stageB(nb, 1, kkn);
    PHASE(buf, 1, 1, false);
    WAITB(4);                       // kh0(t+1) proven; in-flight = kh1(t+1)
    buf = nb;
  }
  asm volatile("s_waitcnt vmcnt(0)" ::: "memory");

  // epilogue: row = bm+wmRow+m*16+fq*4+r ; col = bn+wnCol+n*16+fr
  const int row0 = bm + wmRow + fq * 4;
  const int col0 = bn + wnCol + fr;
  #pragma unroll
  for (int m = 0; m < 8; m++) {
    #pragma unroll
    for (int n = 0; n < 4; n++) {
      const int col = col0 + n * 16;
      #pragma unroll
      for (int r = 0; r < 4; r++) {
        const int row = row0 + m * 16 + r;
        float v = acc[m][n][r];
        if constexpr (EPI == EPI_QKV) {
          if (col < 2048) v = (v > 0.f) ? (v + 1.f) : __expf(v);  // phi = elu+1
          ((short*)outp)[(size_t)row * ldo + col] = f2b(v);
        } else if constexpr (EPI == EPI_RES) {
          ((short*)outp)[(size_t)row * ldo + col] =
              f2b(v + ((const float*)resid)[(size_t)row * ldo + col]);
        } else if constexpr (EPI == EPI_GELU) {
          v += bias[col];
          v = 0.5f * v * (1.f + erff(v * 0.70710678118654752f));
          ((short*)outp)[(size_t)row * ldo + col] = f2b(v);
        } else {  // EPI_FC2: bias + bf16 residual -> fp32 d_out
          v += bias[col] + b2f(((const short*)resid)[(size_t)row * ldo + col]);
          ((float*)outp)[(size_t)row * ldo + col] = v;
        }
      }
    }
  }
}

// ---------- kv partial reduce v3: 1024 blocks x 512 rows ----------
__global__ __launch_bounds__(256) void kv_reduce(
    const short* __restrict__ qkv, float* __restrict__ kv_part,
    float* __restrict__ ksum_part) {
  const int blk = blockIdx.x;  // 1024 = 64 bh * 16 chunks
  const int bh = blk >> 4, chunk = blk & 15;
  const int b = bh >> 4, h = bh & 15;
  const size_t rowbase = (size_t)b * 8192 + (size_t)chunk * 512;
  const int kcol = 1024 + h * 64, vcol = 2048 + h * 64;
  __shared__ float Klf[64][68];
  __shared__ float Vlf[64][68];
  const int tid = threadIdx.x;
  const int dk = tid >> 2, dq = tid & 3;
  float acc[16] = {};
  float ks = 0.f;
  for (int t = 0; t < 8; t++) {
    #pragma unroll
    for (int i = 0; i < 2; i++) {
      const int s = i * 256 + tid;
      const int r = s >> 3, seg = (s & 7) * 8;
      const size_t g = (rowbase + t * 64 + r) * 3072;
      const s16x8 k8 = *(const s16x8*)&qkv[g + kcol + seg];
      const s16x8 v8 = *(const s16x8*)&qkv[g + vcol + seg];
      float4 ka, kb, va, vb;
      ka.x = b2f(k8[0]); ka.y = b2f(k8[1]); ka.z = b2f(k8[2]); ka.w = b2f(k8[3]);
      kb.x = b2f(k8[4]); kb.y = b2f(k8[5]); kb.z = b2f(k8[6]); kb.w = b2f(k8[7]);
      va.x = b2f(v8[0]); va.y = b2f(v8[1]); va.z = b2f(v8[2]); va.w = b2f(v8[3]);
      vb.x = b2f(v8[4]); vb.y = b2f(v8[5]); vb.z = b2f(v8[6]); vb.w = b2f(v8[7]);
      *(float4*)&Klf[r][seg] = ka;
      *(float4*)&Klf[r][seg + 4] = kb;
      *(float4*)&Vlf[r][seg] = va;
      *(float4*)&Vlf[r][seg + 4] = vb;
    }
    __syncthreads();
    #pragma unroll 4
    for (int n = 0; n < 64; n++) {
      const float kval = Klf[n][dk];
      if (dq == 0) ks += kval;
      const float4 v0 = *(const float4*)&Vlf[n][dq * 16];
      const float4 v1 = *(const float4*)&Vlf[n][dq * 16 + 4];
      const float4 v2 = *(const float4*)&Vlf[n][dq * 16 + 8];
      const float4 v3 = *(const float4*)&Vlf[n][dq * 16 + 12];
      acc[0]  = fmaf(kval, v0.x, acc[0]);
      acc[1]  = fmaf(kval, v0.y, acc[1]);
      acc[2]  = fmaf(kval, v0.z, acc[2]);
      acc[3]  = fmaf(kval, v0.w, acc[3]);
      acc[4]  = fmaf(kval, v1.x, acc[4]);
      acc[5]  = fmaf(kval, v1.y, acc[5]);
      acc[6]  = fmaf(kval, v1.z, acc[6]);
      acc[7]  = fmaf(kval, v1.w, acc[7]);
      acc[8]  = fmaf(kval, v2.x, acc[8]);
      acc[9]  = fmaf(kval, v2.y, acc[9]);
      acc[10] = fmaf(kval, v2.z, acc[10]);
      acc[11] = fmaf(kval, v2.w, acc[11]);
      acc[12] = fmaf(kval, v3.x, acc[12]);
      acc[13] = fmaf(kval, v3.y, acc[13]);
      acc[14] = fmaf(kval, v3.z, acc[14]);
      acc[15] = fmaf(kval, v3.w, acc[15]);
    }
    __syncthreads();
  }
  float* dst = kv_part + (size_t)blk * 4096 + dk * 64 + dq * 16;
  #pragma unroll
  for (int j = 0; j < 16; j++) dst[j] = acc[j];
  if (dq == 0) ksum_part[(size_t)blk * 64 + dk] = ks;
}

// ---------- kv finalize: reduce 16 partials -> bf16 kv^T, pre-swizzled ----------
__global__ __launch_bounds__(256) void kv_finalize(
    const float* __restrict__ kv_part, const float* __restrict__ ksum_part,
    short* __restrict__ kvT_g, float* __restrict__ ksum_f) {
  const int bh = blockIdx.x >> 2, dg = blockIdx.x & 3;
  const int tid = threadIdx.x;
  const int e = tid & 63, j4 = tid >> 6;
  const int d0 = dg * 16 + j4 * 4;
  float a0 = 0.f, a1 = 0.f, a2 = 0.f, a3 = 0.f;
  const float* base = kv_part + (size_t)bh * 16 * 4096 + d0 * 64 + e;
  for (int c = 0; c < 16; c++) {
    const float* p = base + (size_t)c * 4096;
    a0 += p[0]; a1 += p[64]; a2 += p[128]; a3 += p[192];
  }
  s16x4 o; o.x = f2b(a0); o.y = f2b(a1); o.z = f2b(a2); o.w = f2b(a3);
  char* dstb = (char*)(kvT_g + (size_t)bh * 4096);
  *(s16x4*)(dstb + e * 128 + ((2 * d0) ^ ((e & 7) << 4))) = o;
  if (tid < 16) {
    const int d = dg * 16 + tid;
    float s = 0.f;
    for (int c = 0; c < 16; c++)
      s += ksum_part[((size_t)bh * 16 + c) * 64 + d];
    ksum_f[bh * 64 + d] = s;
  }
}

// ---------- attention apply via MFMA: ao = (Q @ kv) / (Q . ksum + eps) ----------
__global__ __launch_bounds__(256) void attn_apply_mfma(
    const short* __restrict__ qkv, const short* __restrict__ kvT_g,
    const float* __restrict__ ksum_f, short* __restrict__ ao) {
  __shared__ alignas(16) short kvs[4096];
  __shared__ float ksl[64];
  const int blk = blockIdx.x;
  const int bh = blk >> 5, rc = blk & 31;
  const int b = bh >> 4, h = bh & 15;
  const int tid = threadIdx.x, lane = tid & 63, w = tid >> 6;
  const int fr = lane & 15, fq = lane >> 4;

  GLD16(kvT_g + (size_t)bh * 4096 + tid * 8, (char*)kvs + tid * 16);
  GLD16(kvT_g + (size_t)bh * 4096 + (256 + tid) * 8, (char*)kvs + (256 + tid) * 16);
  if (tid < 64) ksl[tid] = ksum_f[bh * 64 + tid];
  __syncthreads();

  bf16x8 bkv[4][2], bns[2];
  #pragma unroll
  for (int n = 0; n < 4; n++) {
    #pragma unroll
    for (int c = 0; c < 2; c++) {
      const int e = n * 16 + fr;
      const int byteoff = e * 128 + ((c * 64 + fq * 16) ^ ((e & 7) << 4));
      bkv[n][c] = *(const bf16x8*)((const char*)kvs + byteoff);
    }
  }
  #pragma unroll
  for (int c = 0; c < 2; c++) {
    s16x8 ts = {0, 0, 0, 0, 0, 0, 0, 0};
    if (fr == 0) {
      #pragma unroll
      for (int j = 0; j < 8; j++) ts[j] = f2b(ksl[c * 32 + fq * 8 + j]);
    }
    bns[c] = asbf(ts);
  }

  f32x4 acc[4][4] = {};
  f32x4 nacc[4] = {};
  const size_t rowbase = (size_t)b * 8192 + (size_t)rc * 256 + w * 64;
  const int qcol = h * 64;
  #pragma unroll
  for (int m = 0; m < 4; m++) {
    const short* qrow = qkv + (rowbase + m * 16 + fr) * 3072 + qcol + fq * 8;
    const bf16x8 a0 = *(const bf16x8*)qrow;
    const bf16x8 a1 = *(const bf16x8*)(qrow + 32);
    #pragma unroll
    for (int n = 0; n < 4; n++) {
      acc[m][n] = __builtin_amdgcn_mfma_f32_16x16x32_bf16(a0, bkv[n][0], acc[m][n], 0, 0, 0);
      acc[m][n] = __builtin_amdgcn_mfma_f32_16x16x32_bf16(a1, bkv[n][1], acc[m][n], 0, 0, 0);
    }
    nacc[m] = __builtin_amdgcn_mfma_f32_16x16x32_bf16(a0, bns[0], nacc[m], 0, 0, 0);
    nacc[m] = __builtin_amdgcn_mfma_f32_16x16x32_bf16(a1, bns[1], nacc[m], 0, 0, 0);
  }

  #pragma unroll
  for (int m = 0; m < 4; m++) {
    #pragma unroll
    for (int r = 0; r < 4; r++) {
      const float nv = __shfl(nacc[m][r], lane & 48) + 1e-6f;
      const float rn = 1.f / nv;
      const size_t row = rowbase + m * 16 + fq * 4 + r;
      #pragma unroll
      for (int n = 0; n < 4; n++)
        ao[row * 1024 + qcol + n * 16 + fr] = f2b(acc[m][n][r] * rn);
    }
  }
}

// ---------- launcher ----------
extern "C" void kernel_launch(void* const* d_in, const int* in_sizes, int n_in,
                              void* d_out, int out_size, void* d_ws, size_t ws_size,
                              hipStream_t stream) {
  (void)in_sizes; (void)n_in; (void)out_size; (void)ws_size;
  const float* src   = (const float*)d_in[0];
  const float* ln1_w = (const float*)d_in[1];
  const float* ln1_b = (const float*)d_in[2];
  const float* wq    = (const float*)d_in[3];
  const float* wk    = (const float*)d_in[4];
  const float* wv    = (const float*)d_in[5];
  const float* wo    = (const float*)d_in[6];
  const float* ln2_w = (const float*)d_in[7];
  const float* ln2_b = (const float*)d_in[8];
  const float* fc1_w = (const float*)d_in[9];
  const float* fc1_b = (const float*)d_in[10];
  const float* fc2_w = (const float*)d_in[11];
  const float* fc2_b = (const float*)d_in[12];

  char* ws = (char*)d_ws;
  short* wqkvT     = (short*)(ws + 0);            // [3072][1024] bf16
  short* woT       = (short*)(ws + 6291456);      // [1024][1024]
  short* fc1T      = (short*)(ws + 8388608);      // [4096][1024]
  short* fc2T      = (short*)(ws + 16777216);     // [1024][4096]
  short* kvT_g     = (short*)(ws + 25165824);     // [64][4096] bf16 swizzled
  float* ksum_f    = (float*)(ws + 25690112);     // [64][64]
  float* kv_part   = (float*)(ws + 25706496);     // [1024][4096] fp32 (16.8MB)
  float* ksum_part = (float*)(ws + 42483712);     // [1024][64]
  short* hbuf      = (short*)(ws + 93863936);     // [32768][1024] bf16 (h / ao / h2)
  short* src2b     = (short*)(ws + 160972800);    // [32768][1024] bf16 (residual)
  short* qkv       = (short*)(ws + 295190528);    // [32768][3072] bf16
  short* a1c       = (short*)(ws + 295190528);    // [16384][4096] bf16 (aliases qkv)
  // high-water: 496,517,120 bytes (< 503,447,552 proven in round 1)

  const dim3 tb(256);
  const dim3 tb512(512);

  // weights -> bf16 transposed
  transpose_cvt<<<dim3(32, 32), tb, 0, stream>>>(wq, wqkvT, 1024, 1024);
  transpose_cvt<<<dim3(32, 32), tb, 0, stream>>>(wk, wqkvT + 1024 * 1024, 1024, 1024);
  transpose_cvt<<<dim3(32, 32), tb, 0, stream>>>(wv, wqkvT + 2048 * 1024, 1024, 1024);
  transpose_cvt<<<dim3(32, 32), tb, 0, stream>>>(wo, woT, 1024, 1024);
  transpose_cvt<<<dim3(128, 32), tb, 0, stream>>>(fc1_w, fc1T, 1024, 4096);
  transpose_cvt<<<dim3(32, 128), tb, 0, stream>>>(fc2_w, fc2T, 4096, 1024);

  // LN1: src (fp32) -> h (bf16)
  ln_kernel<<<32768, tb, 0, stream>>>(src, ln1_w, ln1_b, hbuf);

  // QKV projection + phi on Q,K   (M=32768, N=3072, K=1024; gx=128, gy=12)
  gemm256<EPI_QKV><<<dim3(1536), tb512, 0, stream>>>(
      hbuf, 1024, wqkvT, 1024, 3072, 128, nullptr, nullptr, qkv);

  // kv / ksum: partial reduce (v3) -> finalize (bf16, transposed, swizzled)
  kv_reduce<<<1024, tb, 0, stream>>>(qkv, kv_part, ksum_part);
  kv_finalize<<<256, tb, 0, stream>>>(kv_part, ksum_part, kvT_g, ksum_f);

  // attention apply via MFMA -> ao (hbuf)
  attn_apply_mfma<<<2048, tb, 0, stream>>>(qkv, kvT_g, ksum_f, hbuf);

  // O projection + residual(src fp32) -> src2b (bf16)  (gx=128, gy=4)
  gemm256<EPI_RES><<<dim3(512), tb512, 0, stream>>>(
      hbuf, 1024, woT, 1024, 1024, 128, nullptr, src, src2b);

  // LN2: src2b (bf16) -> h2 (bf16, reuse hbuf)
  ln_kernel_b<<<32768, tb, 0, stream>>>(src2b, ln2_w, ln2_b, hbuf);

  // MLP, 2 chunks of 16384 rows (a1c aliases dead qkv buffer)
  for (int c = 0; c < 2; c++) {
    const size_t mo = (size_t)c * 16384;
    // FC1: M=16384, N=4096, K=1024; gx=64, gy=16
    gemm256<EPI_GELU><<<dim3(1024), tb512, 0, stream>>>(
        hbuf + mo * 1024, 1024, fc1T, 1024, 4096, 64, fc1_b, nullptr, a1c);
    // FC2: M=16384, N=1024, K=4096; gx=64, gy=4 ; bf16 residual
    gemm256<EPI_FC2><<<dim3(256), tb512, 0, stream>>>(
        a1c, 4096, fc2T, 4096, 1024, 64, fc2_b, src2b + mo * 1024,
        (float*)d_out + mo * 1024);
  }
}

// Round 17
// 1106.704 us; speedup vs baseline: 1.0707x; 1.0156x over previous
//
#include <hip/hip_runtime.h>
#include <hip/hip_bf16.h>

// ---------- types ----------
typedef __attribute__((ext_vector_type(8))) short s16x8;
typedef __attribute__((ext_vector_type(4))) short s16x4;
typedef __attribute__((ext_vector_type(8))) __bf16 bf16x8;
typedef __attribute__((ext_vector_type(4))) float f32x4;

__device__ __forceinline__ float b2f(short s) {
  union { float f; unsigned u; } x;
  x.u = ((unsigned)(unsigned short)s) << 16;
  return x.f;
}
__device__ __forceinline__ short f2b(float f) {
  union { float f; unsigned u; } x;
  x.f = f;
  unsigned r = x.u + 0x7fff + ((x.u >> 16) & 1);  // RNE
  return (short)(r >> 16);
}
__device__ __forceinline__ bf16x8 asbf(s16x8 v) {
  union { s16x8 s; bf16x8 b; } u; u.s = v; return u.b;
}

#define GLD16(g, l) __builtin_amdgcn_global_load_lds( \
    (const __attribute__((address_space(1))) void*)(g), \
    (__attribute__((address_space(3))) void*)(l), 16, 0, 0)

#define WAITB(N) do { \
  asm volatile("s_waitcnt vmcnt(" #N ")" ::: "memory"); \
  __builtin_amdgcn_s_barrier(); \
  asm volatile("" ::: "memory"); \
} while (0)

// ---------- weight transpose + fp32->bf16 : out[c][r] = in[r][c] ----------
__global__ __launch_bounds__(256) void transpose_cvt(
    const float* __restrict__ in, short* __restrict__ out, int R, int C) {
  __shared__ float tile[32][33];
  const int tx = threadIdx.x & 31, ty = threadIdx.x >> 5;  // 32x8
  const int c0 = blockIdx.x * 32, r0 = blockIdx.y * 32;
  #pragma unroll
  for (int i = 0; i < 32; i += 8)
    tile[ty + i][tx] = in[(size_t)(r0 + ty + i) * C + c0 + tx];
  __syncthreads();
  #pragma unroll
  for (int i = 0; i < 32; i += 8)
    out[(size_t)(c0 + ty + i) * R + r0 + tx] = f2b(tile[tx][ty + i]);
}

// ---------- 3-way 1024x1024 transpose (wq,wk,wv -> wqkvT) ----------
__global__ __launch_bounds__(256) void transpose_cvt3(
    const float* __restrict__ i0, const float* __restrict__ i1,
    const float* __restrict__ i2, short* __restrict__ out) {
  __shared__ float tile[32][33];
  const float* in = (blockIdx.z == 0) ? i0 : (blockIdx.z == 1) ? i1 : i2;
  short* o = out + (size_t)blockIdx.z * 1024 * 1024;
  const int tx = threadIdx.x & 31, ty = threadIdx.x >> 5;
  const int c0 = blockIdx.x * 32, r0 = blockIdx.y * 32;
  #pragma unroll
  for (int i = 0; i < 32; i += 8)
    tile[ty + i][tx] = in[(size_t)(r0 + ty + i) * 1024 + c0 + tx];
  __syncthreads();
  #pragma unroll
  for (int i = 0; i < 32; i += 8)
    o[(size_t)(c0 + ty + i) * 1024 + r0 + tx] = f2b(tile[tx][ty + i]);
}

// ---------- layernorm: fp32 [rows][1024] -> bf16 ----------
__global__ __launch_bounds__(256) void ln_kernel(
    const float* __restrict__ x, const float* __restrict__ gw,
    const float* __restrict__ gb, short* __restrict__ out) {
  const int row = blockIdx.x;
  const int tid = threadIdx.x;
  const float4 v = ((const float4*)(x + (size_t)row * 1024))[tid];
  float s = v.x + v.y + v.z + v.w;
  float s2 = v.x * v.x + v.y * v.y + v.z * v.z + v.w * v.w;
  #pragma unroll
  for (int o = 32; o > 0; o >>= 1) {
    s += __shfl_xor(s, o);
    s2 += __shfl_xor(s2, o);
  }
  __shared__ float red[2][4];
  const int lane = tid & 63, wid = tid >> 6;
  if (lane == 0) { red[0][wid] = s; red[1][wid] = s2; }
  __syncthreads();
  s = red[0][0] + red[0][1] + red[0][2] + red[0][3];
  s2 = red[1][0] + red[1][1] + red[1][2] + red[1][3];
  const float mu = s * (1.f / 1024.f);
  const float rstd = rsqrtf(s2 * (1.f / 1024.f) - mu * mu + 1e-5f);
  const float4 wv4 = ((const float4*)gw)[tid];
  const float4 bv4 = ((const float4*)gb)[tid];
  s16x4 o4;
  o4.x = f2b((v.x - mu) * rstd * wv4.x + bv4.x);
  o4.y = f2b((v.y - mu) * rstd * wv4.y + bv4.y);
  o4.z = f2b((v.z - mu) * rstd * wv4.z + bv4.z);
  o4.w = f2b((v.w - mu) * rstd * wv4.w + bv4.w);
  *(s16x4*)(out + (size_t)row * 1024 + tid * 4) = o4;
}

// ---------- layernorm, bf16 input: [rows][1024] bf16 -> bf16 ----------
__global__ __launch_bounds__(256) void ln_kernel_b(
    const short* __restrict__ x, const float* __restrict__ gw,
    const float* __restrict__ gb, short* __restrict__ out) {
  const int row = blockIdx.x;
  const int tid = threadIdx.x;
  const s16x4 xv = *(const s16x4*)(x + (size_t)row * 1024 + tid * 4);
  float v0 = b2f(xv.x), v1 = b2f(xv.y), v2 = b2f(xv.z), v3 = b2f(xv.w);
  float s = v0 + v1 + v2 + v3;
  float s2 = v0 * v0 + v1 * v1 + v2 * v2 + v3 * v3;
  #pragma unroll
  for (int o = 32; o > 0; o >>= 1) {
    s += __shfl_xor(s, o);
    s2 += __shfl_xor(s2, o);
  }
  __shared__ float red[2][4];
  const int lane = tid & 63, wid = tid >> 6;
  if (lane == 0) { red[0][wid] = s; red[1][wid] = s2; }
  __syncthreads();
  s = red[0][0] + red[0][1] + red[0][2] + red[0][3];
  s2 = red[1][0] + red[1][1] + red[1][2] + red[1][3];
  const float mu = s * (1.f / 1024.f);
  const float rstd = rsqrtf(s2 * (1.f / 1024.f) - mu * mu + 1e-5f);
  const float4 wv4 = ((const float4*)gw)[tid];
  const float4 bv4 = ((const float4*)gb)[tid];
  s16x4 o4;
  o4.x = f2b((v0 - mu) * rstd * wv4.x + bv4.x);
  o4.y = f2b((v1 - mu) * rstd * wv4.y + bv4.y);
  o4.z = f2b((v2 - mu) * rstd * wv4.z + bv4.z);
  o4.w = f2b((v3 - mu) * rstd * wv4.w + bv4.w);
  *(s16x4*)(out + (size_t)row * 1024 + tid * 4) = o4;
}

// ---------- 256x256 bf16 MFMA GEMM (r13/r16-proven: 16x16x32, super-tile map) ----------
// Best-known across 16 rounds: r3 loop ledger + L2 super-tile mapping (r11)
// + bijective XCD swizzle + both-sides XOR LDS swizzle. 43% MfmaUtil plateau;
// 8 structure variants (schedules/occupancy/tiles/instr-shape) exhausted.

enum { EPI_QKV = 0, EPI_RES = 1, EPI_GELU = 2, EPI_FC2 = 3 };

#define PHASE(BUFB, MH, KS, LOADB) do { \
    const int ab = (BUFB) + (KS) * 16384; \
    const int bb = (BUFB) + 32768 + (KS) * 16384; \
    if (LOADB) { \
      _Pragma("unroll") \
      for (int n = 0; n < 4; n++) { \
        const int row = wnCol + n * 16 + fr; \
        const int g = row >> 1; \
        const int s = (((row & 1) << 2) | fq) ^ (g & 7); \
        bfv[n] = *(const bf16x8*)(ldsc + bb + g * 128 + s * 16); \
      } \
    } \
    bf16x8 af[4]; \
    _Pragma("unroll") \
    for (int mm = 0; mm < 4; mm++) { \
      const int row = wmRow + (MH) * 64 + mm * 16 + fr; \
      const int g = row >> 1; \
      const int s = (((row & 1) << 2) | fq) ^ (g & 7); \
      af[mm] = *(const bf16x8*)(ldsc + ab + g * 128 + s * 16); \
    } \
    __builtin_amdgcn_s_setprio(1); \
    _Pragma("unroll") \
    for (int mm = 0; mm < 4; mm++) \
      _Pragma("unroll") \
      for (int n = 0; n < 4; n++) \
        acc[(MH) * 4 + mm][n] = __builtin_amdgcn_mfma_f32_16x16x32_bf16( \
            af[mm], bfv[n], acc[(MH) * 4 + mm][n], 0, 0, 0); \
    __builtin_amdgcn_s_setprio(0); \
  } while (0)

template <int EPI>
__global__ __launch_bounds__(512, 2) void gemm256(
    const short* __restrict__ A, int lda,
    const short* __restrict__ Bt, int K, int ldo, int gx,
    const float* __restrict__ bias,
    const void* __restrict__ resid,
    void* __restrict__ outp) {
  __shared__ alignas(16) short lds[65536];  // 128 KiB
  const int tid = threadIdx.x;
  const int lane = tid & 63, wave = tid >> 6;
  // T1: bijective XCD swizzle (grid % 8 == 0 for all launches)
  const int cpx = (int)gridDim.x >> 3;
  const int bid = ((int)blockIdx.x & 7) * cpx + ((int)blockIdx.x >> 3);
  // L2 super-tile mapping: 32-block groups of 8bm x 4bn
  const int sgx = gx >> 3;
  const int grp = bid >> 5;
  const int sm = grp % sgx, sn = grp / sgx;
  const int bm = (sm * 8 + (bid & 7)) * 256;
  const int bn = (sn * 4 + ((bid & 31) >> 3)) * 256;
  const int wmRow = (wave >> 2) * 128;
  const int wnCol = (wave & 3) * 64;
  const int fr = lane & 15, fq = lane >> 4;

  // staging constants: inverse-swizzled global source, linear LDS dest
  const int sg = tid >> 3;
  const int s0 = (tid & 7) ^ (sg & 7);
  const int srow = 2 * sg + (s0 >> 2);   // load 0 row; load 1 adds 128
  const int scol = (s0 & 3) * 8;
  const int sdst = tid * 16;

  const char* ldsc = (const char*)lds;
  char* ldsw = (char*)lds;

  f32x4 acc[8][4] = {};
  bf16x8 bfv[4];

  auto stageA = [&](int bufb, int kh, int kk) {
    const short* g = A + (size_t)(bm + srow) * lda + kk + kh * 32 + scol;
    char* l = ldsw + bufb + kh * 16384 + sdst;
    GLD16(g, l);
    GLD16(g + (size_t)128 * lda, l + 8192);
  };
  auto stageB = [&](int bufb, int kh, int kk) {
    const short* g = Bt + (size_t)(bn + srow) * K + kk + kh * 32 + scol;
    char* l = ldsw + bufb + 32768 + kh * 16384 + sdst;
    GLD16(g, l);
    GLD16(g + (size_t)128 * K, l + 8192);
  };

  const int NT = K >> 6;
  // prologue: full tile 0 into buf0; WAITB(4) -> kh0 proven, kh1 in flight
  stageA(0, 0, 0);
  stageB(0, 0, 0);
  stageA(0, 1, 0);
  stageB(0, 1, 0);
  WAITB(4);

  int buf = 0;
  for (int t = 0; t < NT; ++t) {
    const int kkn = (t + 1 < NT) ? ((t + 1) << 6) : 0;  // clamp keeps counts uniform
    const int nb = buf ^ 65536;
    stageA(nb, 0, kkn);
    PHASE(buf, 0, 0, true);
    stageB(nb, 0, kkn);
    PHASE(buf, 1, 0, false);
    WAITB(8);                       // kh1(t) proven (r3 ledger)
    stageA(nb, 1, kkn);
    PHASE(buf, 0, 1, true);
    stageB(nb, 1, kkn);
    PHASE(buf, 1, 1, false);
    WAITB(4);                       // kh0(t+1) proven; in-flight = kh1(t+1)
    buf = nb;
  }
  asm volatile("s_waitcnt vmcnt(0)" ::: "memory");

  // epilogue: row = bm+wmRow+m*16+fq*4+r ; col = bn+wnCol+n*16+fr
  const int row0 = bm + wmRow + fq * 4;
  const int col0 = bn + wnCol + fr;
  #pragma unroll
  for (int m = 0; m < 8; m++) {
    #pragma unroll
    for (int n = 0; n < 4; n++) {
      const int col = col0 + n * 16;
      #pragma unroll
      for (int r = 0; r < 4; r++) {
        const int row = row0 + m * 16 + r;
        float v = acc[m][n][r];
        if constexpr (EPI == EPI_QKV) {
          if (col < 2048) v = (v > 0.f) ? (v + 1.f) : __expf(v);  // phi = elu+1
          ((short*)outp)[(size_t)row * ldo + col] = f2b(v);
        } else if constexpr (EPI == EPI_RES) {
          ((short*)outp)[(size_t)row * ldo + col] =
              f2b(v + ((const float*)resid)[(size_t)row * ldo + col]);
        } else if constexpr (EPI == EPI_GELU) {
          v += bias[col];
          v = 0.5f * v * (1.f + erff(v * 0.70710678118654752f));
          ((short*)outp)[(size_t)row * ldo + col] = f2b(v);
        } else {  // EPI_FC2: bias + bf16 residual -> fp32 d_out
          v += bias[col] + b2f(((const short*)resid)[(size_t)row * ldo + col]);
          ((float*)outp)[(size_t)row * ldo + col] = v;
        }
      }
    }
  }
}

// ---------- kv partial reduce v3: 1024 blocks x 512 rows ----------
__global__ __launch_bounds__(256) void kv_reduce(
    const short* __restrict__ qkv, float* __restrict__ kv_part,
    float* __restrict__ ksum_part) {
  const int blk = blockIdx.x;  // 1024 = 64 bh * 16 chunks
  const int bh = blk >> 4, chunk = blk & 15;
  const int b = bh >> 4, h = bh & 15;
  const size_t rowbase = (size_t)b * 8192 + (size_t)chunk * 512;
  const int kcol = 1024 + h * 64, vcol = 2048 + h * 64;
  __shared__ float Klf[64][68];
  __shared__ float Vlf[64][68];
  const int tid = threadIdx.x;
  const int dk = tid >> 2, dq = tid & 3;
  float acc[16] = {};
  float ks = 0.f;
  for (int t = 0; t < 8; t++) {
    #pragma unroll
    for (int i = 0; i < 2; i++) {
      const int s = i * 256 + tid;
      const int r = s >> 3, seg = (s & 7) * 8;
      const size_t g = (rowbase + t * 64 + r) * 3072;
      const s16x8 k8 = *(const s16x8*)&qkv[g + kcol + seg];
      const s16x8 v8 = *(const s16x8*)&qkv[g + vcol + seg];
      float4 ka, kb, va, vb;
      ka.x = b2f(k8[0]); ka.y = b2f(k8[1]); ka.z = b2f(k8[2]); ka.w = b2f(k8[3]);
      kb.x = b2f(k8[4]); kb.y = b2f(k8[5]); kb.z = b2f(k8[6]); kb.w = b2f(k8[7]);
      va.x = b2f(v8[0]); va.y = b2f(v8[1]); va.z = b2f(v8[2]); va.w = b2f(v8[3]);
      vb.x = b2f(v8[4]); vb.y = b2f(v8[5]); vb.z = b2f(v8[6]); vb.w = b2f(v8[7]);
      *(float4*)&Klf[r][seg] = ka;
      *(float4*)&Klf[r][seg + 4] = kb;
      *(float4*)&Vlf[r][seg] = va;
      *(float4*)&Vlf[r][seg + 4] = vb;
    }
    __syncthreads();
    #pragma unroll 4
    for (int n = 0; n < 64; n++) {
      const float kval = Klf[n][dk];
      if (dq == 0) ks += kval;
      const float4 v0 = *(const float4*)&Vlf[n][dq * 16];
      const float4 v1 = *(const float4*)&Vlf[n][dq * 16 + 4];
      const float4 v2 = *(const float4*)&Vlf[n][dq * 16 + 8];
      const float4 v3 = *(const float4*)&Vlf[n][dq * 16 + 12];
      acc[0]  = fmaf(kval, v0.x, acc[0]);
      acc[1]  = fmaf(kval, v0.y, acc[1]);
      acc[2]  = fmaf(kval, v0.z, acc[2]);
      acc[3]  = fmaf(kval, v0.w, acc[3]);
      acc[4]  = fmaf(kval, v1.x, acc[4]);
      acc[5]  = fmaf(kval, v1.y, acc[5]);
      acc[6]  = fmaf(kval, v1.z, acc[6]);
      acc[7]  = fmaf(kval, v1.w, acc[7]);
      acc[8]  = fmaf(kval, v2.x, acc[8]);
      acc[9]  = fmaf(kval, v2.y, acc[9]);
      acc[10] = fmaf(kval, v2.z, acc[10]);
      acc[11] = fmaf(kval, v2.w, acc[11]);
      acc[12] = fmaf(kval, v3.x, acc[12]);
      acc[13] = fmaf(kval, v3.y, acc[13]);
      acc[14] = fmaf(kval, v3.z, acc[14]);
      acc[15] = fmaf(kval, v3.w, acc[15]);
    }
    __syncthreads();
  }
  float* dst = kv_part + (size_t)blk * 4096 + dk * 64 + dq * 16;
  #pragma unroll
  for (int j = 0; j < 16; j++) dst[j] = acc[j];
  if (dq == 0) ksum_part[(size_t)blk * 64 + dk] = ks;
}

// ---------- kv finalize: reduce 16 partials -> bf16 kv^T, pre-swizzled ----------
__global__ __launch_bounds__(256) void kv_finalize(
    const float* __restrict__ kv_part, const float* __restrict__ ksum_part,
    short* __restrict__ kvT_g, float* __restrict__ ksum_f) {
  const int bh = blockIdx.x >> 2, dg = blockIdx.x & 3;
  const int tid = threadIdx.x;
  const int e = tid & 63, j4 = tid >> 6;
  const int d0 = dg * 16 + j4 * 4;
  float a0 = 0.f, a1 = 0.f, a2 = 0.f, a3 = 0.f;
  const float* base = kv_part + (size_t)bh * 16 * 4096 + d0 * 64 + e;
  for (int c = 0; c < 16; c++) {
    const float* p = base + (size_t)c * 4096;
    a0 += p[0]; a1 += p[64]; a2 += p[128]; a3 += p[192];
  }
  s16x4 o; o.x = f2b(a0); o.y = f2b(a1); o.z = f2b(a2); o.w = f2b(a3);
  char* dstb = (char*)(kvT_g + (size_t)bh * 4096);
  *(s16x4*)(dstb + e * 128 + ((2 * d0) ^ ((e & 7) << 4))) = o;
  if (tid < 16) {
    const int d = dg * 16 + tid;
    float s = 0.f;
    for (int c = 0; c < 16; c++)
      s += ksum_part[((size_t)bh * 16 + c) * 64 + d];
    ksum_f[bh * 64 + d] = s;
  }
}

// ---------- attention apply via MFMA: ao = (Q @ kv) / (Q . ksum + eps) ----------
__global__ __launch_bounds__(256) void attn_apply_mfma(
    const short* __restrict__ qkv, const short* __restrict__ kvT_g,
    const float* __restrict__ ksum_f, short* __restrict__ ao) {
  __shared__ alignas(16) short kvs[4096];
  __shared__ float ksl[64];
  const int blk = blockIdx.x;
  const int bh = blk >> 5, rc = blk & 31;
  const int b = bh >> 4, h = bh & 15;
  const int tid = threadIdx.x, lane = tid & 63, w = tid >> 6;
  const int fr = lane & 15, fq = lane >> 4;

  GLD16(kvT_g + (size_t)bh * 4096 + tid * 8, (char*)kvs + tid * 16);
  GLD16(kvT_g + (size_t)bh * 4096 + (256 + tid) * 8, (char*)kvs + (256 + tid) * 16);
  if (tid < 64) ksl[tid] = ksum_f[bh * 64 + tid];
  __syncthreads();

  bf16x8 bkv[4][2], bns[2];
  #pragma unroll
  for (int n = 0; n < 4; n++) {
    #pragma unroll
    for (int c = 0; c < 2; c++) {
      const int e = n * 16 + fr;
      const int byteoff = e * 128 + ((c * 64 + fq * 16) ^ ((e & 7) << 4));
      bkv[n][c] = *(const bf16x8*)((const char*)kvs + byteoff);
    }
  }
  #pragma unroll
  for (int c = 0; c < 2; c++) {
    s16x8 ts = {0, 0, 0, 0, 0, 0, 0, 0};
    if (fr == 0) {
      #pragma unroll
      for (int j = 0; j < 8; j++) ts[j] = f2b(ksl[c * 32 + fq * 8 + j]);
    }
    bns[c] = asbf(ts);
  }

  f32x4 acc[4][4] = {};
  f32x4 nacc[4] = {};
  const size_t rowbase = (size_t)b * 8192 + (size_t)rc * 256 + w * 64;
  const int qcol = h * 64;
  #pragma unroll
  for (int m = 0; m < 4; m++) {
    const short* qrow = qkv + (rowbase + m * 16 + fr) * 3072 + qcol + fq * 8;
    const bf16x8 a0 = *(const bf16x8*)qrow;
    const bf16x8 a1 = *(const bf16x8*)(qrow + 32);
    #pragma unroll
    for (int n = 0; n < 4; n++) {
      acc[m][n] = __builtin_amdgcn_mfma_f32_16x16x32_bf16(a0, bkv[n][0], acc[m][n], 0, 0, 0);
      acc[m][n] = __builtin_amdgcn_mfma_f32_16x16x32_bf16(a1, bkv[n][1], acc[m][n], 0, 0, 0);
    }
    nacc[m] = __builtin_amdgcn_mfma_f32_16x16x32_bf16(a0, bns[0], nacc[m], 0, 0, 0);
    nacc[m] = __builtin_amdgcn_mfma_f32_16x16x32_bf16(a1, bns[1], nacc[m], 0, 0, 0);
  }

  #pragma unroll
  for (int m = 0; m < 4; m++) {
    #pragma unroll
    for (int r = 0; r < 4; r++) {
      const float nv = __shfl(nacc[m][r], lane & 48) + 1e-6f;
      const float rn = 1.f / nv;
      const size_t row = rowbase + m * 16 + fq * 4 + r;
      #pragma unroll
      for (int n = 0; n < 4; n++)
        ao[row * 1024 + qcol + n * 16 + fr] = f2b(acc[m][n][r] * rn);
    }
  }
}

// ---------- launcher ----------
extern "C" void kernel_launch(void* const* d_in, const int* in_sizes, int n_in,
                              void* d_out, int out_size, void* d_ws, size_t ws_size,
                              hipStream_t stream) {
  (void)in_sizes; (void)n_in; (void)out_size; (void)ws_size;
  const float* src   = (const float*)d_in[0];
  const float* ln1_w = (const float*)d_in[1];
  const float* ln1_b = (const float*)d_in[2];
  const float* wq    = (const float*)d_in[3];
  const float* wk    = (const float*)d_in[4];
  const float* wv    = (const float*)d_in[5];
  const float* wo    = (const float*)d_in[6];
  const float* ln2_w = (const float*)d_in[7];
  const float* ln2_b = (const float*)d_in[8];
  const float* fc1_w = (const float*)d_in[9];
  const float* fc1_b = (const float*)d_in[10];
  const float* fc2_w = (const float*)d_in[11];
  const float* fc2_b = (const float*)d_in[12];

  char* ws = (char*)d_ws;
  short* wqkvT     = (short*)(ws + 0);            // [3072][1024] bf16
  short* woT       = (short*)(ws + 6291456);      // [1024][1024]
  short* fc1T      = (short*)(ws + 8388608);      // [4096][1024]
  short* fc2T      = (short*)(ws + 16777216);     // [1024][4096]
  short* kvT_g     = (short*)(ws + 25165824);     // [64][4096] bf16 swizzled
  float* ksum_f    = (float*)(ws + 25690112);     // [64][64]
  float* kv_part   = (float*)(ws + 25706496);     // [1024][4096] fp32 (16.8MB)
  float* ksum_part = (float*)(ws + 42483712);     // [1024][64]
  short* hbuf      = (short*)(ws + 93863936);     // [32768][1024] bf16 (h / ao / h2)
  short* src2b     = (short*)(ws + 160972800);    // [32768][1024] bf16 (residual)
  short* a1        = (short*)(ws + 228081664);    // [32768][4096] bf16 (268MB)
  short* qkv       = (short*)(ws + 295190528);    // [32768][3072] bf16 (dead
                                                  //   before FC1; a1 aliases it)
  // high-water: 496,517,120 bytes (= proven bound; a1 ends exactly there)

  const dim3 tb(256);
  const dim3 tb512(512);

  // weights -> bf16 transposed (wq/wk/wv in one 3-deep launch)
  transpose_cvt3<<<dim3(32, 32, 3), tb, 0, stream>>>(wq, wk, wv, wqkvT);
  transpose_cvt<<<dim3(32, 32), tb, 0, stream>>>(wo, woT, 1024, 1024);
  transpose_cvt<<<dim3(128, 32), tb, 0, stream>>>(fc1_w, fc1T, 1024, 4096);
  transpose_cvt<<<dim3(32, 128), tb, 0, stream>>>(fc2_w, fc2T, 4096, 1024);

  // LN1: src (fp32) -> h (bf16)
  ln_kernel<<<32768, tb, 0, stream>>>(src, ln1_w, ln1_b, hbuf);

  // QKV projection + phi on Q,K   (M=32768, N=3072, K=1024; gx=128, gy=12)
  gemm256<EPI_QKV><<<dim3(1536), tb512, 0, stream>>>(
      hbuf, 1024, wqkvT, 1024, 3072, 128, nullptr, nullptr, qkv);

  // kv / ksum: partial reduce (v3) -> finalize (bf16, transposed, swizzled)
  kv_reduce<<<1024, tb, 0, stream>>>(qkv, kv_part, ksum_part);
  kv_finalize<<<256, tb, 0, stream>>>(kv_part, ksum_part, kvT_g, ksum_f);

  // attention apply via MFMA -> ao (hbuf)
  attn_apply_mfma<<<2048, tb, 0, stream>>>(qkv, kvT_g, ksum_f, hbuf);

  // O projection + residual(src fp32) -> src2b (bf16)  (gx=128, gy=4)
  gemm256<EPI_RES><<<dim3(512), tb512, 0, stream>>>(
      hbuf, 1024, woT, 1024, 1024, 128, nullptr, src, src2b);

  // LN2: src2b (bf16) -> h2 (bf16, reuse hbuf)
  ln_kernel_b<<<32768, tb, 0, stream>>>(src2b, ln2_w, ln2_b, hbuf);

  // MLP, single pass over all 32768 rows (a1 aliases dead qkv region)
  // FC1: M=32768, N=4096, K=1024; gx=128, gy=16 -> grid 2048
  gemm256<EPI_GELU><<<dim3(2048), tb512, 0, stream>>>(
      hbuf, 1024, fc1T, 1024, 4096, 128, fc1_b, nullptr, a1);
  // FC2: M=32768, N=1024, K=4096; gx=128, gy=4 -> grid 512 ; bf16 residual
  gemm256<EPI_FC2><<<dim3(512), tb512, 0, stream>>>(
      a1, 4096, fc2T, 4096, 1024, 128, fc2_b, src2b, (float*)d_out);
}

// Round 18
// 1078.649 us; speedup vs baseline: 1.0985x; 1.0260x over previous
//
#include <hip/hip_runtime.h>
#include <hip/hip_bf16.h>

// ---------- types ----------
typedef __attribute__((ext_vector_type(8))) short s16x8;
typedef __attribute__((ext_vector_type(4))) short s16x4;
typedef __attribute__((ext_vector_type(8))) __bf16 bf16x8;
typedef __attribute__((ext_vector_type(4))) float f32x4;

__device__ __forceinline__ float b2f(short s) {
  union { float f; unsigned u; } x;
  x.u = ((unsigned)(unsigned short)s) << 16;
  return x.f;
}
__device__ __forceinline__ short f2b(float f) {
  union { float f; unsigned u; } x;
  x.f = f;
  unsigned r = x.u + 0x7fff + ((x.u >> 16) & 1);  // RNE
  return (short)(r >> 16);
}
__device__ __forceinline__ bf16x8 asbf(s16x8 v) {
  union { s16x8 s; bf16x8 b; } u; u.s = v; return u.b;
}

// exact-GELU via Abramowitz-Stegun 7.1.26 erf (|err_erf| < 1.5e-7):
// ~15 VALU ops vs libm erff's ~25-30 — the FC1 epilogue was ~90us of
// exposed VALU (r17: VALUBusy 50%, MfmaUtil 31%).
__device__ __forceinline__ float gelu_exact(float x) {
  const float z = fabsf(x) * 0.70710678118654752f;
  const float t = 1.f / fmaf(0.3275911f, z, 1.f);
  float p = fmaf(1.061405429f, t, -1.453152027f);
  p = fmaf(p, t, 1.421413741f);
  p = fmaf(p, t, -0.284496736f);
  p = fmaf(p, t, 0.254829592f);
  p *= t;
  const float e = __expf(-z * z);
  const float erfz = copysignf(fmaf(-p, e, 1.f), x);
  return 0.5f * x * (1.f + erfz);
}

#define GLD16(g, l) __builtin_amdgcn_global_load_lds( \
    (const __attribute__((address_space(1))) void*)(g), \
    (__attribute__((address_space(3))) void*)(l), 16, 0, 0)

#define WAITB(N) do { \
  asm volatile("s_waitcnt vmcnt(" #N ")" ::: "memory"); \
  __builtin_amdgcn_s_barrier(); \
  asm volatile("" ::: "memory"); \
} while (0)

// ---------- weight transpose + fp32->bf16 : out[c][r] = in[r][c] ----------
__global__ __launch_bounds__(256) void transpose_cvt(
    const float* __restrict__ in, short* __restrict__ out, int R, int C) {
  __shared__ float tile[32][33];
  const int tx = threadIdx.x & 31, ty = threadIdx.x >> 5;  // 32x8
  const int c0 = blockIdx.x * 32, r0 = blockIdx.y * 32;
  #pragma unroll
  for (int i = 0; i < 32; i += 8)
    tile[ty + i][tx] = in[(size_t)(r0 + ty + i) * C + c0 + tx];
  __syncthreads();
  #pragma unroll
  for (int i = 0; i < 32; i += 8)
    out[(size_t)(c0 + ty + i) * R + r0 + tx] = f2b(tile[tx][ty + i]);
}

// ---------- 3-way 1024x1024 transpose (wq,wk,wv -> wqkvT) ----------
__global__ __launch_bounds__(256) void transpose_cvt3(
    const float* __restrict__ i0, const float* __restrict__ i1,
    const float* __restrict__ i2, short* __restrict__ out) {
  __shared__ float tile[32][33];
  const float* in = (blockIdx.z == 0) ? i0 : (blockIdx.z == 1) ? i1 : i2;
  short* o = out + (size_t)blockIdx.z * 1024 * 1024;
  const int tx = threadIdx.x & 31, ty = threadIdx.x >> 5;
  const int c0 = blockIdx.x * 32, r0 = blockIdx.y * 32;
  #pragma unroll
  for (int i = 0; i < 32; i += 8)
    tile[ty + i][tx] = in[(size_t)(r0 + ty + i) * 1024 + c0 + tx];
  __syncthreads();
  #pragma unroll
  for (int i = 0; i < 32; i += 8)
    o[(size_t)(c0 + ty + i) * 1024 + r0 + tx] = f2b(tile[tx][ty + i]);
}

// ---------- layernorm: fp32 [rows][1024] -> bf16 ----------
__global__ __launch_bounds__(256) void ln_kernel(
    const float* __restrict__ x, const float* __restrict__ gw,
    const float* __restrict__ gb, short* __restrict__ out) {
  const int row = blockIdx.x;
  const int tid = threadIdx.x;
  const float4 v = ((const float4*)(x + (size_t)row * 1024))[tid];
  float s = v.x + v.y + v.z + v.w;
  float s2 = v.x * v.x + v.y * v.y + v.z * v.z + v.w * v.w;
  #pragma unroll
  for (int o = 32; o > 0; o >>= 1) {
    s += __shfl_xor(s, o);
    s2 += __shfl_xor(s2, o);
  }
  __shared__ float red[2][4];
  const int lane = tid & 63, wid = tid >> 6;
  if (lane == 0) { red[0][wid] = s; red[1][wid] = s2; }
  __syncthreads();
  s = red[0][0] + red[0][1] + red[0][2] + red[0][3];
  s2 = red[1][0] + red[1][1] + red[1][2] + red[1][3];
  const float mu = s * (1.f / 1024.f);
  const float rstd = rsqrtf(s2 * (1.f / 1024.f) - mu * mu + 1e-5f);
  const float4 wv4 = ((const float4*)gw)[tid];
  const float4 bv4 = ((const float4*)gb)[tid];
  s16x4 o4;
  o4.x = f2b((v.x - mu) * rstd * wv4.x + bv4.x);
  o4.y = f2b((v.y - mu) * rstd * wv4.y + bv4.y);
  o4.z = f2b((v.z - mu) * rstd * wv4.z + bv4.z);
  o4.w = f2b((v.w - mu) * rstd * wv4.w + bv4.w);
  *(s16x4*)(out + (size_t)row * 1024 + tid * 4) = o4;
}

// ---------- layernorm, bf16 input: [rows][1024] bf16 -> bf16 ----------
__global__ __launch_bounds__(256) void ln_kernel_b(
    const short* __restrict__ x, const float* __restrict__ gw,
    const float* __restrict__ gb, short* __restrict__ out) {
  const int row = blockIdx.x;
  const int tid = threadIdx.x;
  const s16x4 xv = *(const s16x4*)(x + (size_t)row * 1024 + tid * 4);
  float v0 = b2f(xv.x), v1 = b2f(xv.y), v2 = b2f(xv.z), v3 = b2f(xv.w);
  float s = v0 + v1 + v2 + v3;
  float s2 = v0 * v0 + v1 * v1 + v2 * v2 + v3 * v3;
  #pragma unroll
  for (int o = 32; o > 0; o >>= 1) {
    s += __shfl_xor(s, o);
    s2 += __shfl_xor(s2, o);
  }
  __shared__ float red[2][4];
  const int lane = tid & 63, wid = tid >> 6;
  if (lane == 0) { red[0][wid] = s; red[1][wid] = s2; }
  __syncthreads();
  s = red[0][0] + red[0][1] + red[0][2] + red[0][3];
  s2 = red[1][0] + red[1][1] + red[1][2] + red[1][3];
  const float mu = s * (1.f / 1024.f);
  const float rstd = rsqrtf(s2 * (1.f / 1024.f) - mu * mu + 1e-5f);
  const float4 wv4 = ((const float4*)gw)[tid];
  const float4 bv4 = ((const float4*)gb)[tid];
  s16x4 o4;
  o4.x = f2b((v0 - mu) * rstd * wv4.x + bv4.x);
  o4.y = f2b((v1 - mu) * rstd * wv4.y + bv4.y);
  o4.z = f2b((v2 - mu) * rstd * wv4.z + bv4.z);
  o4.w = f2b((v3 - mu) * rstd * wv4.w + bv4.w);
  *(s16x4*)(out + (size_t)row * 1024 + tid * 4) = o4;
}

// ---------- 256x256 bf16 MFMA GEMM (r13/r16-proven: 16x16x32, super-tile map) ----------
enum { EPI_QKV = 0, EPI_RES = 1, EPI_GELU = 2, EPI_FC2 = 3 };

#define PHASE(BUFB, MH, KS, LOADB) do { \
    const int ab = (BUFB) + (KS) * 16384; \
    const int bb = (BUFB) + 32768 + (KS) * 16384; \
    if (LOADB) { \
      _Pragma("unroll") \
      for (int n = 0; n < 4; n++) { \
        const int row = wnCol + n * 16 + fr; \
        const int g = row >> 1; \
        const int s = (((row & 1) << 2) | fq) ^ (g & 7); \
        bfv[n] = *(const bf16x8*)(ldsc + bb + g * 128 + s * 16); \
      } \
    } \
    bf16x8 af[4]; \
    _Pragma("unroll") \
    for (int mm = 0; mm < 4; mm++) { \
      const int row = wmRow + (MH) * 64 + mm * 16 + fr; \
      const int g = row >> 1; \
      const int s = (((row & 1) << 2) | fq) ^ (g & 7); \
      af[mm] = *(const bf16x8*)(ldsc + ab + g * 128 + s * 16); \
    } \
    __builtin_amdgcn_s_setprio(1); \
    _Pragma("unroll") \
    for (int mm = 0; mm < 4; mm++) \
      _Pragma("unroll") \
      for (int n = 0; n < 4; n++) \
        acc[(MH) * 4 + mm][n] = __builtin_amdgcn_mfma_f32_16x16x32_bf16( \
            af[mm], bfv[n], acc[(MH) * 4 + mm][n], 0, 0, 0); \
    __builtin_amdgcn_s_setprio(0); \
  } while (0)

template <int EPI>
__global__ __launch_bounds__(512, 2) void gemm256(
    const short* __restrict__ A, int lda,
    const short* __restrict__ Bt, int K, int ldo, int gx,
    const float* __restrict__ bias,
    const void* __restrict__ resid,
    void* __restrict__ outp) {
  __shared__ alignas(16) short lds[65536];  // 128 KiB
  const int tid = threadIdx.x;
  const int lane = tid & 63, wave = tid >> 6;
  // T1: bijective XCD swizzle (grid % 8 == 0 for all launches)
  const int cpx = (int)gridDim.x >> 3;
  const int bid = ((int)blockIdx.x & 7) * cpx + ((int)blockIdx.x >> 3);
  // L2 super-tile mapping: 32-block groups of 8bm x 4bn
  const int sgx = gx >> 3;
  const int grp = bid >> 5;
  const int sm = grp % sgx, sn = grp / sgx;
  const int bm = (sm * 8 + (bid & 7)) * 256;
  const int bn = (sn * 4 + ((bid & 31) >> 3)) * 256;
  const int wmRow = (wave >> 2) * 128;
  const int wnCol = (wave & 3) * 64;
  const int fr = lane & 15, fq = lane >> 4;

  // staging constants: inverse-swizzled global source, linear LDS dest
  const int sg = tid >> 3;
  const int s0 = (tid & 7) ^ (sg & 7);
  const int srow = 2 * sg + (s0 >> 2);   // load 0 row; load 1 adds 128
  const int scol = (s0 & 3) * 8;
  const int sdst = tid * 16;

  const char* ldsc = (const char*)lds;
  char* ldsw = (char*)lds;

  f32x4 acc[8][4] = {};
  bf16x8 bfv[4];

  auto stageA = [&](int bufb, int kh, int kk) {
    const short* g = A + (size_t)(bm + srow) * lda + kk + kh * 32 + scol;
    char* l = ldsw + bufb + kh * 16384 + sdst;
    GLD16(g, l);
    GLD16(g + (size_t)128 * lda, l + 8192);
  };
  auto stageB = [&](int bufb, int kh, int kk) {
    const short* g = Bt + (size_t)(bn + srow) * K + kk + kh * 32 + scol;
    char* l = ldsw + bufb + 32768 + kh * 16384 + sdst;
    GLD16(g, l);
    GLD16(g + (size_t)128 * K, l + 8192);
  };

  const int NT = K >> 6;
  // prologue: full tile 0 into buf0; WAITB(4) -> kh0 proven, kh1 in flight
  stageA(0, 0, 0);
  stageB(0, 0, 0);
  stageA(0, 1, 0);
  stageB(0, 1, 0);
  WAITB(4);

  int buf = 0;
  for (int t = 0; t < NT; ++t) {
    const int kkn = (t + 1 < NT) ? ((t + 1) << 6) : 0;  // clamp keeps counts uniform
    const int nb = buf ^ 65536;
    stageA(nb, 0, kkn);
    PHASE(buf, 0, 0, true);
    stageB(nb, 0, kkn);
    PHASE(buf, 1, 0, false);
    WAITB(8);                       // kh1(t) proven (r3 ledger)
    stageA(nb, 1, kkn);
    PHASE(buf, 0, 1, true);
    stageB(nb, 1, kkn);
    PHASE(buf, 1, 1, false);
    WAITB(4);                       // kh0(t+1) proven; in-flight = kh1(t+1)
    buf = nb;
  }
  asm volatile("s_waitcnt vmcnt(0)" ::: "memory");

  // epilogue: row = bm+wmRow+m*16+fq*4+r ; col = bn+wnCol+n*16+fr
  const int row0 = bm + wmRow + fq * 4;
  const int col0 = bn + wnCol + fr;
  #pragma unroll
  for (int m = 0; m < 8; m++) {
    #pragma unroll
    for (int n = 0; n < 4; n++) {
      const int col = col0 + n * 16;
      #pragma unroll
      for (int r = 0; r < 4; r++) {
        const int row = row0 + m * 16 + r;
        float v = acc[m][n][r];
        if constexpr (EPI == EPI_QKV) {
          if (col < 2048) v = (v > 0.f) ? (v + 1.f) : __expf(v);  // phi = elu+1
          ((short*)outp)[(size_t)row * ldo + col] = f2b(v);
        } else if constexpr (EPI == EPI_RES) {
          ((short*)outp)[(size_t)row * ldo + col] =
              f2b(v + ((const float*)resid)[(size_t)row * ldo + col]);
        } else if constexpr (EPI == EPI_GELU) {
          v = gelu_exact(v + bias[col]);
          ((short*)outp)[(size_t)row * ldo + col] = f2b(v);
        } else {  // EPI_FC2: bias + bf16 residual -> fp32 d_out
          v += bias[col] + b2f(((const short*)resid)[(size_t)row * ldo + col]);
          ((float*)outp)[(size_t)row * ldo + col] = v;
        }
      }
    }
  }
}

// ---------- kv partial reduce v3: 1024 blocks x 512 rows ----------
__global__ __launch_bounds__(256) void kv_reduce(
    const short* __restrict__ qkv, float* __restrict__ kv_part,
    float* __restrict__ ksum_part) {
  const int blk = blockIdx.x;  // 1024 = 64 bh * 16 chunks
  const int bh = blk >> 4, chunk = blk & 15;
  const int b = bh >> 4, h = bh & 15;
  const size_t rowbase = (size_t)b * 8192 + (size_t)chunk * 512;
  const int kcol = 1024 + h * 64, vcol = 2048 + h * 64;
  __shared__ float Klf[64][68];
  __shared__ float Vlf[64][68];
  const int tid = threadIdx.x;
  const int dk = tid >> 2, dq = tid & 3;
  float acc[16] = {};
  float ks = 0.f;
  for (int t = 0; t < 8; t++) {
    #pragma unroll
    for (int i = 0; i < 2; i++) {
      const int s = i * 256 + tid;
      const int r = s >> 3, seg = (s & 7) * 8;
      const size_t g = (rowbase + t * 64 + r) * 3072;
      const s16x8 k8 = *(const s16x8*)&qkv[g + kcol + seg];
      const s16x8 v8 = *(const s16x8*)&qkv[g + vcol + seg];
      float4 ka, kb, va, vb;
      ka.x = b2f(k8[0]); ka.y = b2f(k8[1]); ka.z = b2f(k8[2]); ka.w = b2f(k8[3]);
      kb.x = b2f(k8[4]); kb.y = b2f(k8[5]); kb.z = b2f(k8[6]); kb.w = b2f(k8[7]);
      va.x = b2f(v8[0]); va.y = b2f(v8[1]); va.z = b2f(v8[2]); va.w = b2f(v8[3]);
      vb.x = b2f(v8[4]); vb.y = b2f(v8[5]); vb.z = b2f(v8[6]); vb.w = b2f(v8[7]);
      *(float4*)&Klf[r][seg] = ka;
      *(float4*)&Klf[r][seg + 4] = kb;
      *(float4*)&Vlf[r][seg] = va;
      *(float4*)&Vlf[r][seg + 4] = vb;
    }
    __syncthreads();
    #pragma unroll 4
    for (int n = 0; n < 64; n++) {
      const float kval = Klf[n][dk];
      if (dq == 0) ks += kval;
      const float4 v0 = *(const float4*)&Vlf[n][dq * 16];
      const float4 v1 = *(const float4*)&Vlf[n][dq * 16 + 4];
      const float4 v2 = *(const float4*)&Vlf[n][dq * 16 + 8];
      const float4 v3 = *(const float4*)&Vlf[n][dq * 16 + 12];
      acc[0]  = fmaf(kval, v0.x, acc[0]);
      acc[1]  = fmaf(kval, v0.y, acc[1]);
      acc[2]  = fmaf(kval, v0.z, acc[2]);
      acc[3]  = fmaf(kval, v0.w, acc[3]);
      acc[4]  = fmaf(kval, v1.x, acc[4]);
      acc[5]  = fmaf(kval, v1.y, acc[5]);
      acc[6]  = fmaf(kval, v1.z, acc[6]);
      acc[7]  = fmaf(kval, v1.w, acc[7]);
      acc[8]  = fmaf(kval, v2.x, acc[8]);
      acc[9]  = fmaf(kval, v2.y, acc[9]);
      acc[10] = fmaf(kval, v2.z, acc[10]);
      acc[11] = fmaf(kval, v2.w, acc[11]);
      acc[12] = fmaf(kval, v3.x, acc[12]);
      acc[13] = fmaf(kval, v3.y, acc[13]);
      acc[14] = fmaf(kval, v3.z, acc[14]);
      acc[15] = fmaf(kval, v3.w, acc[15]);
    }
    __syncthreads();
  }
  float* dst = kv_part + (size_t)blk * 4096 + dk * 64 + dq * 16;
  #pragma unroll
  for (int j = 0; j < 16; j++) dst[j] = acc[j];
  if (dq == 0) ksum_part[(size_t)blk * 64 + dk] = ks;
}

// ---------- kv finalize: reduce 16 partials -> bf16 kv^T, pre-swizzled ----------
__global__ __launch_bounds__(256) void kv_finalize(
    const float* __restrict__ kv_part, const float* __restrict__ ksum_part,
    short* __restrict__ kvT_g, float* __restrict__ ksum_f) {
  const int bh = blockIdx.x >> 2, dg = blockIdx.x & 3;
  const int tid = threadIdx.x;
  const int e = tid & 63, j4 = tid >> 6;
  const int d0 = dg * 16 + j4 * 4;
  float a0 = 0.f, a1 = 0.f, a2 = 0.f, a3 = 0.f;
  const float* base = kv_part + (size_t)bh * 16 * 4096 + d0 * 64 + e;
  for (int c = 0; c < 16; c++) {
    const float* p = base + (size_t)c * 4096;
    a0 += p[0]; a1 += p[64]; a2 += p[128]; a3 += p[192];
  }
  s16x4 o; o.x = f2b(a0); o.y = f2b(a1); o.z = f2b(a2); o.w = f2b(a3);
  char* dstb = (char*)(kvT_g + (size_t)bh * 4096);
  *(s16x4*)(dstb + e * 128 + ((2 * d0) ^ ((e & 7) << 4))) = o;
  if (tid < 16) {
    const int d = dg * 16 + tid;
    float s = 0.f;
    for (int c = 0; c < 16; c++)
      s += ksum_part[((size_t)bh * 16 + c) * 64 + d];
    ksum_f[bh * 64 + d] = s;
  }
}

// ---------- attention apply via MFMA: ao = (Q @ kv) / (Q . ksum + eps) ----------
__global__ __launch_bounds__(256) void attn_apply_mfma(
    const short* __restrict__ qkv, const short* __restrict__ kvT_g,
    const float* __restrict__ ksum_f, short* __restrict__ ao) {
  __shared__ alignas(16) short kvs[4096];
  __shared__ float ksl[64];
  const int blk = blockIdx.x;
  const int bh = blk >> 5, rc = blk & 31;
  const int b = bh >> 4, h = bh & 15;
  const int tid = threadIdx.x, lane = tid & 63, w = tid >> 6;
  const int fr = lane & 15, fq = lane >> 4;

  GLD16(kvT_g + (size_t)bh * 4096 + tid * 8, (char*)kvs + tid * 16);
  GLD16(kvT_g + (size_t)bh * 4096 + (256 + tid) * 8, (char*)kvs + (256 + tid) * 16);
  if (tid < 64) ksl[tid] = ksum_f[bh * 64 + tid];
  __syncthreads();

  bf16x8 bkv[4][2], bns[2];
  #pragma unroll
  for (int n = 0; n < 4; n++) {
    #pragma unroll
    for (int c = 0; c < 2; c++) {
      const int e = n * 16 + fr;
      const int byteoff = e * 128 + ((c * 64 + fq * 16) ^ ((e & 7) << 4));
      bkv[n][c] = *(const bf16x8*)((const char*)kvs + byteoff);
    }
  }
  #pragma unroll
  for (int c = 0; c < 2; c++) {
    s16x8 ts = {0, 0, 0, 0, 0, 0, 0, 0};
    if (fr == 0) {
      #pragma unroll
      for (int j = 0; j < 8; j++) ts[j] = f2b(ksl[c * 32 + fq * 8 + j]);
    }
    bns[c] = asbf(ts);
  }

  f32x4 acc[4][4] = {};
  f32x4 nacc[4] = {};
  const size_t rowbase = (size_t)b * 8192 + (size_t)rc * 256 + w * 64;
  const int qcol = h * 64;
  #pragma unroll
  for (int m = 0; m < 4; m++) {
    const short* qrow = qkv + (rowbase + m * 16 + fr) * 3072 + qcol + fq * 8;
    const bf16x8 a0 = *(const bf16x8*)qrow;
    const bf16x8 a1 = *(const bf16x8*)(qrow + 32);
    #pragma unroll
    for (int n = 0; n < 4; n++) {
      acc[m][n] = __builtin_amdgcn_mfma_f32_16x16x32_bf16(a0, bkv[n][0], acc[m][n], 0, 0, 0);
      acc[m][n] = __builtin_amdgcn_mfma_f32_16x16x32_bf16(a1, bkv[n][1], acc[m][n], 0, 0, 0);
    }
    nacc[m] = __builtin_amdgcn_mfma_f32_16x16x32_bf16(a0, bns[0], nacc[m], 0, 0, 0);
    nacc[m] = __builtin_amdgcn_mfma_f32_16x16x32_bf16(a1, bns[1], nacc[m], 0, 0, 0);
  }

  #pragma unroll
  for (int m = 0; m < 4; m++) {
    #pragma unroll
    for (int r = 0; r < 4; r++) {
      const float nv = __shfl(nacc[m][r], lane & 48) + 1e-6f;
      const float rn = 1.f / nv;
      const size_t row = rowbase + m * 16 + fq * 4 + r;
      #pragma unroll
      for (int n = 0; n < 4; n++)
        ao[row * 1024 + qcol + n * 16 + fr] = f2b(acc[m][n][r] * rn);
    }
  }
}

// ---------- launcher ----------
extern "C" void kernel_launch(void* const* d_in, const int* in_sizes, int n_in,
                              void* d_out, int out_size, void* d_ws, size_t ws_size,
                              hipStream_t stream) {
  (void)in_sizes; (void)n_in; (void)out_size; (void)ws_size;
  const float* src   = (const float*)d_in[0];
  const float* ln1_w = (const float*)d_in[1];
  const float* ln1_b = (const float*)d_in[2];
  const float* wq    = (const float*)d_in[3];
  const float* wk    = (const float*)d_in[4];
  const float* wv    = (const float*)d_in[5];
  const float* wo    = (const float*)d_in[6];
  const float* ln2_w = (const float*)d_in[7];
  const float* ln2_b = (const float*)d_in[8];
  const float* fc1_w = (const float*)d_in[9];
  const float* fc1_b = (const float*)d_in[10];
  const float* fc2_w = (const float*)d_in[11];
  const float* fc2_b = (const float*)d_in[12];

  char* ws = (char*)d_ws;
  short* wqkvT     = (short*)(ws + 0);            // [3072][1024] bf16
  short* woT       = (short*)(ws + 6291456);      // [1024][1024]
  short* fc1T      = (short*)(ws + 8388608);      // [4096][1024]
  short* fc2T      = (short*)(ws + 16777216);     // [1024][4096]
  short* kvT_g     = (short*)(ws + 25165824);     // [64][4096] bf16 swizzled
  float* ksum_f    = (float*)(ws + 25690112);     // [64][64]
  float* kv_part   = (float*)(ws + 25706496);     // [1024][4096] fp32 (16.8MB)
  float* ksum_part = (float*)(ws + 42483712);     // [1024][64]
  short* hbuf      = (short*)(ws + 93863936);     // [32768][1024] bf16 (h / ao / h2)
  short* src2b     = (short*)(ws + 160972800);    // [32768][1024] bf16 (residual)
  short* a1        = (short*)(ws + 228081664);    // [32768][4096] bf16 (268MB)
  short* qkv       = (short*)(ws + 295190528);    // [32768][3072] bf16 (dead
                                                  //   before FC1; a1 aliases it)
  // high-water: 496,517,120 bytes (= proven bound; a1 ends exactly there)

  const dim3 tb(256);
  const dim3 tb512(512);

  // weights -> bf16 transposed (wq/wk/wv in one 3-deep launch)
  transpose_cvt3<<<dim3(32, 32, 3), tb, 0, stream>>>(wq, wk, wv, wqkvT);
  transpose_cvt<<<dim3(32, 32), tb, 0, stream>>>(wo, woT, 1024, 1024);
  transpose_cvt<<<dim3(128, 32), tb, 0, stream>>>(fc1_w, fc1T, 1024, 4096);
  transpose_cvt<<<dim3(32, 128), tb, 0, stream>>>(fc2_w, fc2T, 4096, 1024);

  // LN1: src (fp32) -> h (bf16)
  ln_kernel<<<32768, tb, 0, stream>>>(src, ln1_w, ln1_b, hbuf);

  // QKV projection + phi on Q,K   (M=32768, N=3072, K=1024; gx=128, gy=12)
  gemm256<EPI_QKV><<<dim3(1536), tb512, 0, stream>>>(
      hbuf, 1024, wqkvT, 1024, 3072, 128, nullptr, nullptr, qkv);

  // kv / ksum: partial reduce (v3) -> finalize (bf16, transposed, swizzled)
  kv_reduce<<<1024, tb, 0, stream>>>(qkv, kv_part, ksum_part);
  kv_finalize<<<256, tb, 0, stream>>>(kv_part, ksum_part, kvT_g, ksum_f);

  // attention apply via MFMA -> ao (hbuf)
  attn_apply_mfma<<<2048, tb, 0, stream>>>(qkv, kvT_g, ksum_f, hbuf);

  // O projection + residual(src fp32) -> src2b (bf16)  (gx=128, gy=4)
  gemm256<EPI_RES><<<dim3(512), tb512, 0, stream>>>(
      hbuf, 1024, woT, 1024, 1024, 128, nullptr, src, src2b);

  // LN2: src2b (bf16) -> h2 (bf16, reuse hbuf)
  ln_kernel_b<<<32768, tb, 0, stream>>>(src2b, ln2_w, ln2_b, hbuf);

  // MLP, single pass over all 32768 rows (a1 aliases dead qkv region)
  // FC1: M=32768, N=4096, K=1024; gx=128, gy=16 -> grid 2048
  gemm256<EPI_GELU><<<dim3(2048), tb512, 0, stream>>>(
      hbuf, 1024, fc1T, 1024, 4096, 128, fc1_b, nullptr, a1);
  // FC2: M=32768, N=1024, K=4096; gx=128, gy=4 -> grid 512 ; bf16 residual
  gemm256<EPI_FC2><<<dim3(512), tb512, 0, stream>>>(
      a1, 4096, fc2T, 4096, 1024, 128, fc2_b, src2b, (float*)d_out);
}

// Round 19
// 1036.136 us; speedup vs baseline: 1.1436x; 1.0410x over previous
//
#include <hip/hip_runtime.h>
#include <hip/hip_bf16.h>

// ---------- types ----------
typedef __attribute__((ext_vector_type(8))) short s16x8;
typedef __attribute__((ext_vector_type(4))) short s16x4;
typedef __attribute__((ext_vector_type(8))) __bf16 bf16x8;
typedef __attribute__((ext_vector_type(4))) float f32x4;

__device__ __forceinline__ float b2f(short s) {
  union { float f; unsigned u; } x;
  x.u = ((unsigned)(unsigned short)s) << 16;
  return x.f;
}
__device__ __forceinline__ short f2b(float f) {
  union { float f; unsigned u; } x;
  x.f = f;
  unsigned r = x.u + 0x7fff + ((x.u >> 16) & 1);  // RNE
  return (short)(r >> 16);
}
__device__ __forceinline__ bf16x8 asbf(s16x8 v) {
  union { s16x8 s; bf16x8 b; } u; u.s = v; return u.b;
}

// GELU, tanh form with HW v_rcp (r18 lesson: 1.f/x without fast-math is the
// ~10-op IEEE div sequence; v_rcp_f32 is 1 op). ~10 VALU ops total.
// gelu(x) = x*(1-r), r = 1/(e^{2g}+1), g = 0.79788456*(x+0.044715x^3).
// |tanh-form - exact| ~3e-4 + ~2ulp rcp: far below bf16 output rounding.
__device__ __forceinline__ float gelu_fast(float x) {
  const float x2 = x * x;
  const float g = 1.5957691216057308f * fmaf(0.044715f * x2, x, x);  // 2*0.79788456*(...)
  const float e = __expf(g);            // e^{2g}
  const float r = __builtin_amdgcn_rcpf(e + 1.f);
  return x * (1.f - r);
}

#define GLD16(g, l) __builtin_amdgcn_global_load_lds( \
    (const __attribute__((address_space(1))) void*)(g), \
    (__attribute__((address_space(3))) void*)(l), 16, 0, 0)

#define WAITB(N) do { \
  asm volatile("s_waitcnt vmcnt(" #N ")" ::: "memory"); \
  __builtin_amdgcn_s_barrier(); \
  asm volatile("" ::: "memory"); \
} while (0)

// ---------- weight transpose + fp32->bf16 : out[c][r] = in[r][c] ----------
__global__ __launch_bounds__(256) void transpose_cvt(
    const float* __restrict__ in, short* __restrict__ out, int R, int C) {
  __shared__ float tile[32][33];
  const int tx = threadIdx.x & 31, ty = threadIdx.x >> 5;  // 32x8
  const int c0 = blockIdx.x * 32, r0 = blockIdx.y * 32;
  #pragma unroll
  for (int i = 0; i < 32; i += 8)
    tile[ty + i][tx] = in[(size_t)(r0 + ty + i) * C + c0 + tx];
  __syncthreads();
  #pragma unroll
  for (int i = 0; i < 32; i += 8)
    out[(size_t)(c0 + ty + i) * R + r0 + tx] = f2b(tile[tx][ty + i]);
}

// ---------- 3-way 1024x1024 transpose (wq,wk,wv -> wqkvT) ----------
__global__ __launch_bounds__(256) void transpose_cvt3(
    const float* __restrict__ i0, const float* __restrict__ i1,
    const float* __restrict__ i2, short* __restrict__ out) {
  __shared__ float tile[32][33];
  const float* in = (blockIdx.z == 0) ? i0 : (blockIdx.z == 1) ? i1 : i2;
  short* o = out + (size_t)blockIdx.z * 1024 * 1024;
  const int tx = threadIdx.x & 31, ty = threadIdx.x >> 5;
  const int c0 = blockIdx.x * 32, r0 = blockIdx.y * 32;
  #pragma unroll
  for (int i = 0; i < 32; i += 8)
    tile[ty + i][tx] = in[(size_t)(r0 + ty + i) * 1024 + c0 + tx];
  __syncthreads();
  #pragma unroll
  for (int i = 0; i < 32; i += 8)
    o[(size_t)(c0 + ty + i) * 1024 + r0 + tx] = f2b(tile[tx][ty + i]);
}

// ---------- layernorm: fp32 [rows][1024] -> bf16 ----------
__global__ __launch_bounds__(256) void ln_kernel(
    const float* __restrict__ x, const float* __restrict__ gw,
    const float* __restrict__ gb, short* __restrict__ out) {
  const int row = blockIdx.x;
  const int tid = threadIdx.x;
  const float4 v = ((const float4*)(x + (size_t)row * 1024))[tid];
  float s = v.x + v.y + v.z + v.w;
  float s2 = v.x * v.x + v.y * v.y + v.z * v.z + v.w * v.w;
  #pragma unroll
  for (int o = 32; o > 0; o >>= 1) {
    s += __shfl_xor(s, o);
    s2 += __shfl_xor(s2, o);
  }
  __shared__ float red[2][4];
  const int lane = tid & 63, wid = tid >> 6;
  if (lane == 0) { red[0][wid] = s; red[1][wid] = s2; }
  __syncthreads();
  s = red[0][0] + red[0][1] + red[0][2] + red[0][3];
  s2 = red[1][0] + red[1][1] + red[1][2] + red[1][3];
  const float mu = s * (1.f / 1024.f);
  const float rstd = rsqrtf(s2 * (1.f / 1024.f) - mu * mu + 1e-5f);
  const float4 wv4 = ((const float4*)gw)[tid];
  const float4 bv4 = ((const float4*)gb)[tid];
  s16x4 o4;
  o4.x = f2b((v.x - mu) * rstd * wv4.x + bv4.x);
  o4.y = f2b((v.y - mu) * rstd * wv4.y + bv4.y);
  o4.z = f2b((v.z - mu) * rstd * wv4.z + bv4.z);
  o4.w = f2b((v.w - mu) * rstd * wv4.w + bv4.w);
  *(s16x4*)(out + (size_t)row * 1024 + tid * 4) = o4;
}

// ---------- layernorm, bf16 input: [rows][1024] bf16 -> bf16 ----------
__global__ __launch_bounds__(256) void ln_kernel_b(
    const short* __restrict__ x, const float* __restrict__ gw,
    const float* __restrict__ gb, short* __restrict__ out) {
  const int row = blockIdx.x;
  const int tid = threadIdx.x;
  const s16x4 xv = *(const s16x4*)(x + (size_t)row * 1024 + tid * 4);
  float v0 = b2f(xv.x), v1 = b2f(xv.y), v2 = b2f(xv.z), v3 = b2f(xv.w);
  float s = v0 + v1 + v2 + v3;
  float s2 = v0 * v0 + v1 * v1 + v2 * v2 + v3 * v3;
  #pragma unroll
  for (int o = 32; o > 0; o >>= 1) {
    s += __shfl_xor(s, o);
    s2 += __shfl_xor(s2, o);
  }
  __shared__ float red[2][4];
  const int lane = tid & 63, wid = tid >> 6;
  if (lane == 0) { red[0][wid] = s; red[1][wid] = s2; }
  __syncthreads();
  s = red[0][0] + red[0][1] + red[0][2] + red[0][3];
  s2 = red[1][0] + red[1][1] + red[1][2] + red[1][3];
  const float mu = s * (1.f / 1024.f);
  const float rstd = rsqrtf(s2 * (1.f / 1024.f) - mu * mu + 1e-5f);
  const float4 wv4 = ((const float4*)gw)[tid];
  const float4 bv4 = ((const float4*)gb)[tid];
  s16x4 o4;
  o4.x = f2b((v0 - mu) * rstd * wv4.x + bv4.x);
  o4.y = f2b((v1 - mu) * rstd * wv4.y + bv4.y);
  o4.z = f2b((v2 - mu) * rstd * wv4.z + bv4.z);
  o4.w = f2b((v3 - mu) * rstd * wv4.w + bv4.w);
  *(s16x4*)(out + (size_t)row * 1024 + tid * 4) = o4;
}

// ---------- 256x256 bf16 MFMA GEMM (r13/r16-proven: 16x16x32, super-tile map) ----------
enum { EPI_QKV = 0, EPI_RES = 1, EPI_GELU = 2, EPI_FC2 = 3 };

#define PHASE(BUFB, MH, KS, LOADB) do { \
    const int ab = (BUFB) + (KS) * 16384; \
    const int bb = (BUFB) + 32768 + (KS) * 16384; \
    if (LOADB) { \
      _Pragma("unroll") \
      for (int n = 0; n < 4; n++) { \
        const int row = wnCol + n * 16 + fr; \
        const int g = row >> 1; \
        const int s = (((row & 1) << 2) | fq) ^ (g & 7); \
        bfv[n] = *(const bf16x8*)(ldsc + bb + g * 128 + s * 16); \
      } \
    } \
    bf16x8 af[4]; \
    _Pragma("unroll") \
    for (int mm = 0; mm < 4; mm++) { \
      const int row = wmRow + (MH) * 64 + mm * 16 + fr; \
      const int g = row >> 1; \
      const int s = (((row & 1) << 2) | fq) ^ (g & 7); \
      af[mm] = *(const bf16x8*)(ldsc + ab + g * 128 + s * 16); \
    } \
    __builtin_amdgcn_s_setprio(1); \
    _Pragma("unroll") \
    for (int mm = 0; mm < 4; mm++) \
      _Pragma("unroll") \
      for (int n = 0; n < 4; n++) \
        acc[(MH) * 4 + mm][n] = __builtin_amdgcn_mfma_f32_16x16x32_bf16( \
            af[mm], bfv[n], acc[(MH) * 4 + mm][n], 0, 0, 0); \
    __builtin_amdgcn_s_setprio(0); \
  } while (0)

template <int EPI>
__global__ __launch_bounds__(512, 2) void gemm256(
    const short* __restrict__ A, int lda,
    const short* __restrict__ Bt, int K, int ldo, int gx,
    const float* __restrict__ bias,
    const void* __restrict__ resid,
    void* __restrict__ outp) {
  __shared__ alignas(16) short lds[65536];  // 128 KiB
  const int tid = threadIdx.x;
  const int lane = tid & 63, wave = tid >> 6;
  // T1: bijective XCD swizzle (grid % 8 == 0 for all launches)
  const int cpx = (int)gridDim.x >> 3;
  const int bid = ((int)blockIdx.x & 7) * cpx + ((int)blockIdx.x >> 3);
  // L2 super-tile mapping: 32-block groups of 8bm x 4bn
  const int sgx = gx >> 3;
  const int grp = bid >> 5;
  const int sm = grp % sgx, sn = grp / sgx;
  const int bm = (sm * 8 + (bid & 7)) * 256;
  const int bn = (sn * 4 + ((bid & 31) >> 3)) * 256;
  const int wmRow = (wave >> 2) * 128;
  const int wnCol = (wave & 3) * 64;
  const int fr = lane & 15, fq = lane >> 4;

  // staging constants: inverse-swizzled global source, linear LDS dest
  const int sg = tid >> 3;
  const int s0 = (tid & 7) ^ (sg & 7);
  const int srow = 2 * sg + (s0 >> 2);   // load 0 row; load 1 adds 128
  const int scol = (s0 & 3) * 8;
  const int sdst = tid * 16;

  const char* ldsc = (const char*)lds;
  char* ldsw = (char*)lds;

  f32x4 acc[8][4] = {};
  bf16x8 bfv[4];

  auto stageA = [&](int bufb, int kh, int kk) {
    const short* g = A + (size_t)(bm + srow) * lda + kk + kh * 32 + scol;
    char* l = ldsw + bufb + kh * 16384 + sdst;
    GLD16(g, l);
    GLD16(g + (size_t)128 * lda, l + 8192);
  };
  auto stageB = [&](int bufb, int kh, int kk) {
    const short* g = Bt + (size_t)(bn + srow) * K + kk + kh * 32 + scol;
    char* l = ldsw + bufb + 32768 + kh * 16384 + sdst;
    GLD16(g, l);
    GLD16(g + (size_t)128 * K, l + 8192);
  };

  const int NT = K >> 6;
  // prologue: full tile 0 into buf0; WAITB(4) -> kh0 proven, kh1 in flight
  stageA(0, 0, 0);
  stageB(0, 0, 0);
  stageA(0, 1, 0);
  stageB(0, 1, 0);
  WAITB(4);

  int buf = 0;
  for (int t = 0; t < NT; ++t) {
    const int kkn = (t + 1 < NT) ? ((t + 1) << 6) : 0;  // clamp keeps counts uniform
    const int nb = buf ^ 65536;
    stageA(nb, 0, kkn);
    PHASE(buf, 0, 0, true);
    stageB(nb, 0, kkn);
    PHASE(buf, 1, 0, false);
    WAITB(8);                       // kh1(t) proven (r3 ledger)
    stageA(nb, 1, kkn);
    PHASE(buf, 0, 1, true);
    stageB(nb, 1, kkn);
    PHASE(buf, 1, 1, false);
    WAITB(4);                       // kh0(t+1) proven; in-flight = kh1(t+1)
    buf = nb;
  }
  asm volatile("s_waitcnt vmcnt(0)" ::: "memory");

  // epilogue: row = bm+wmRow+m*16+fq*4+r ; col = bn+wnCol+n*16+fr
  const int row0 = bm + wmRow + fq * 4;
  const int col0 = bn + wnCol + fr;
  #pragma unroll
  for (int m = 0; m < 8; m++) {
    #pragma unroll
    for (int n = 0; n < 4; n++) {
      const int col = col0 + n * 16;
      #pragma unroll
      for (int r = 0; r < 4; r++) {
        const int row = row0 + m * 16 + r;
        float v = acc[m][n][r];
        if constexpr (EPI == EPI_QKV) {
          if (col < 2048) v = (v > 0.f) ? (v + 1.f) : __expf(v);  // phi = elu+1
          ((short*)outp)[(size_t)row * ldo + col] = f2b(v);
        } else if constexpr (EPI == EPI_RES) {
          ((short*)outp)[(size_t)row * ldo + col] =
              f2b(v + ((const float*)resid)[(size_t)row * ldo + col]);
        } else if constexpr (EPI == EPI_GELU) {
          v = gelu_fast(v + bias[col]);
          ((short*)outp)[(size_t)row * ldo + col] = f2b(v);
        } else {  // EPI_FC2: bias + bf16 residual -> fp32 d_out
          v += bias[col] + b2f(((const short*)resid)[(size_t)row * ldo + col]);
          ((float*)outp)[(size_t)row * ldo + col] = v;
        }
      }
    }
  }
}

// ---------- kv partial reduce v3: 1024 blocks x 512 rows ----------
__global__ __launch_bounds__(256) void kv_reduce(
    const short* __restrict__ qkv, float* __restrict__ kv_part,
    float* __restrict__ ksum_part) {
  const int blk = blockIdx.x;  // 1024 = 64 bh * 16 chunks
  const int bh = blk >> 4, chunk = blk & 15;
  const int b = bh >> 4, h = bh & 15;
  const size_t rowbase = (size_t)b * 8192 + (size_t)chunk * 512;
  const int kcol = 1024 + h * 64, vcol = 2048 + h * 64;
  __shared__ float Klf[64][68];
  __shared__ float Vlf[64][68];
  const int tid = threadIdx.x;
  const int dk = tid >> 2, dq = tid & 3;
  float acc[16] = {};
  float ks = 0.f;
  for (int t = 0; t < 8; t++) {
    #pragma unroll
    for (int i = 0; i < 2; i++) {
      const int s = i * 256 + tid;
      const int r = s >> 3, seg = (s & 7) * 8;
      const size_t g = (rowbase + t * 64 + r) * 3072;
      const s16x8 k8 = *(const s16x8*)&qkv[g + kcol + seg];
      const s16x8 v8 = *(const s16x8*)&qkv[g + vcol + seg];
      float4 ka, kb, va, vb;
      ka.x = b2f(k8[0]); ka.y = b2f(k8[1]); ka.z = b2f(k8[2]); ka.w = b2f(k8[3]);
      kb.x = b2f(k8[4]); kb.y = b2f(k8[5]); kb.z = b2f(k8[6]); kb.w = b2f(k8[7]);
      va.x = b2f(v8[0]); va.y = b2f(v8[1]); va.z = b2f(v8[2]); va.w = b2f(v8[3]);
      vb.x = b2f(v8[4]); vb.y = b2f(v8[5]); vb.z = b2f(v8[6]); vb.w = b2f(v8[7]);
      *(float4*)&Klf[r][seg] = ka;
      *(float4*)&Klf[r][seg + 4] = kb;
      *(float4*)&Vlf[r][seg] = va;
      *(float4*)&Vlf[r][seg + 4] = vb;
    }
    __syncthreads();
    #pragma unroll 4
    for (int n = 0; n < 64; n++) {
      const float kval = Klf[n][dk];
      if (dq == 0) ks += kval;
      const float4 v0 = *(const float4*)&Vlf[n][dq * 16];
      const float4 v1 = *(const float4*)&Vlf[n][dq * 16 + 4];
      const float4 v2 = *(const float4*)&Vlf[n][dq * 16 + 8];
      const float4 v3 = *(const float4*)&Vlf[n][dq * 16 + 12];
      acc[0]  = fmaf(kval, v0.x, acc[0]);
      acc[1]  = fmaf(kval, v0.y, acc[1]);
      acc[2]  = fmaf(kval, v0.z, acc[2]);
      acc[3]  = fmaf(kval, v0.w, acc[3]);
      acc[4]  = fmaf(kval, v1.x, acc[4]);
      acc[5]  = fmaf(kval, v1.y, acc[5]);
      acc[6]  = fmaf(kval, v1.z, acc[6]);
      acc[7]  = fmaf(kval, v1.w, acc[7]);
      acc[8]  = fmaf(kval, v2.x, acc[8]);
      acc[9]  = fmaf(kval, v2.y, acc[9]);
      acc[10] = fmaf(kval, v2.z, acc[10]);
      acc[11] = fmaf(kval, v2.w, acc[11]);
      acc[12] = fmaf(kval, v3.x, acc[12]);
      acc[13] = fmaf(kval, v3.y, acc[13]);
      acc[14] = fmaf(kval, v3.z, acc[14]);
      acc[15] = fmaf(kval, v3.w, acc[15]);
    }
    __syncthreads();
  }
  float* dst = kv_part + (size_t)blk * 4096 + dk * 64 + dq * 16;
  #pragma unroll
  for (int j = 0; j < 16; j++) dst[j] = acc[j];
  if (dq == 0) ksum_part[(size_t)blk * 64 + dk] = ks;
}

// ---------- kv finalize: reduce 16 partials -> bf16 kv^T, pre-swizzled ----------
__global__ __launch_bounds__(256) void kv_finalize(
    const float* __restrict__ kv_part, const float* __restrict__ ksum_part,
    short* __restrict__ kvT_g, float* __restrict__ ksum_f) {
  const int bh = blockIdx.x >> 2, dg = blockIdx.x & 3;
  const int tid = threadIdx.x;
  const int e = tid & 63, j4 = tid >> 6;
  const int d0 = dg * 16 + j4 * 4;
  float a0 = 0.f, a1 = 0.f, a2 = 0.f, a3 = 0.f;
  const float* base = kv_part + (size_t)bh * 16 * 4096 + d0 * 64 + e;
  for (int c = 0; c < 16; c++) {
    const float* p = base + (size_t)c * 4096;
    a0 += p[0]; a1 += p[64]; a2 += p[128]; a3 += p[192];
  }
  s16x4 o; o.x = f2b(a0); o.y = f2b(a1); o.z = f2b(a2); o.w = f2b(a3);
  char* dstb = (char*)(kvT_g + (size_t)bh * 4096);
  *(s16x4*)(dstb + e * 128 + ((2 * d0) ^ ((e & 7) << 4))) = o;
  if (tid < 16) {
    const int d = dg * 16 + tid;
    float s = 0.f;
    for (int c = 0; c < 16; c++)
      s += ksum_part[((size_t)bh * 16 + c) * 64 + d];
    ksum_f[bh * 64 + d] = s;
  }
}

// ---------- attention apply via MFMA: ao = (Q @ kv) / (Q . ksum + eps) ----------
__global__ __launch_bounds__(256) void attn_apply_mfma(
    const short* __restrict__ qkv, const short* __restrict__ kvT_g,
    const float* __restrict__ ksum_f, short* __restrict__ ao) {
  __shared__ alignas(16) short kvs[4096];
  __shared__ float ksl[64];
  const int blk = blockIdx.x;
  const int bh = blk >> 5, rc = blk & 31;
  const int b = bh >> 4, h = bh & 15;
  const int tid = threadIdx.x, lane = tid & 63, w = tid >> 6;
  const int fr = lane & 15, fq = lane >> 4;

  GLD16(kvT_g + (size_t)bh * 4096 + tid * 8, (char*)kvs + tid * 16);
  GLD16(kvT_g + (size_t)bh * 4096 + (256 + tid) * 8, (char*)kvs + (256 + tid) * 16);
  if (tid < 64) ksl[tid] = ksum_f[bh * 64 + tid];
  __syncthreads();

  bf16x8 bkv[4][2], bns[2];
  #pragma unroll
  for (int n = 0; n < 4; n++) {
    #pragma unroll
    for (int c = 0; c < 2; c++) {
      const int e = n * 16 + fr;
      const int byteoff = e * 128 + ((c * 64 + fq * 16) ^ ((e & 7) << 4));
      bkv[n][c] = *(const bf16x8*)((const char*)kvs + byteoff);
    }
  }
  #pragma unroll
  for (int c = 0; c < 2; c++) {
    s16x8 ts = {0, 0, 0, 0, 0, 0, 0, 0};
    if (fr == 0) {
      #pragma unroll
      for (int j = 0; j < 8; j++) ts[j] = f2b(ksl[c * 32 + fq * 8 + j]);
    }
    bns[c] = asbf(ts);
  }

  f32x4 acc[4][4] = {};
  f32x4 nacc[4] = {};
  const size_t rowbase = (size_t)b * 8192 + (size_t)rc * 256 + w * 64;
  const int qcol = h * 64;
  #pragma unroll
  for (int m = 0; m < 4; m++) {
    const short* qrow = qkv + (rowbase + m * 16 + fr) * 3072 + qcol + fq * 8;
    const bf16x8 a0 = *(const bf16x8*)qrow;
    const bf16x8 a1 = *(const bf16x8*)(qrow + 32);
    #pragma unroll
    for (int n = 0; n < 4; n++) {
      acc[m][n] = __builtin_amdgcn_mfma_f32_16x16x32_bf16(a0, bkv[n][0], acc[m][n], 0, 0, 0);
      acc[m][n] = __builtin_amdgcn_mfma_f32_16x16x32_bf16(a1, bkv[n][1], acc[m][n], 0, 0, 0);
    }
    nacc[m] = __builtin_amdgcn_mfma_f32_16x16x32_bf16(a0, bns[0], nacc[m], 0, 0, 0);
    nacc[m] = __builtin_amdgcn_mfma_f32_16x16x32_bf16(a1, bns[1], nacc[m], 0, 0, 0);
  }

  #pragma unroll
  for (int m = 0; m < 4; m++) {
    #pragma unroll
    for (int r = 0; r < 4; r++) {
      const float nv = __shfl(nacc[m][r], lane & 48) + 1e-6f;
      const float rn = 1.f / nv;
      const size_t row = rowbase + m * 16 + fq * 4 + r;
      #pragma unroll
      for (int n = 0; n < 4; n++)
        ao[row * 1024 + qcol + n * 16 + fr] = f2b(acc[m][n][r] * rn);
    }
  }
}

// ---------- launcher ----------
extern "C" void kernel_launch(void* const* d_in, const int* in_sizes, int n_in,
                              void* d_out, int out_size, void* d_ws, size_t ws_size,
                              hipStream_t stream) {
  (void)in_sizes; (void)n_in; (void)out_size; (void)ws_size;
  const float* src   = (const float*)d_in[0];
  const float* ln1_w = (const float*)d_in[1];
  const float* ln1_b = (const float*)d_in[2];
  const float* wq    = (const float*)d_in[3];
  const float* wk    = (const float*)d_in[4];
  const float* wv    = (const float*)d_in[5];
  const float* wo    = (const float*)d_in[6];
  const float* ln2_w = (const float*)d_in[7];
  const float* ln2_b = (const float*)d_in[8];
  const float* fc1_w = (const float*)d_in[9];
  const float* fc1_b = (const float*)d_in[10];
  const float* fc2_w = (const float*)d_in[11];
  const float* fc2_b = (const float*)d_in[12];

  char* ws = (char*)d_ws;
  short* wqkvT     = (short*)(ws + 0);            // [3072][1024] bf16
  short* woT       = (short*)(ws + 6291456);      // [1024][1024]
  short* fc1T      = (short*)(ws + 8388608);      // [4096][1024]
  short* fc2T      = (short*)(ws + 16777216);     // [1024][4096]
  short* kvT_g     = (short*)(ws + 25165824);     // [64][4096] bf16 swizzled
  float* ksum_f    = (float*)(ws + 25690112);     // [64][64]
  float* kv_part   = (float*)(ws + 25706496);     // [1024][4096] fp32 (16.8MB)
  float* ksum_part = (float*)(ws + 42483712);     // [1024][64]
  short* hbuf      = (short*)(ws + 93863936);     // [32768][1024] bf16 (h / ao / h2)
  short* src2b     = (short*)(ws + 160972800);    // [32768][1024] bf16 (residual)
  short* a1        = (short*)(ws + 228081664);    // [32768][4096] bf16 (268MB)
  short* qkv       = (short*)(ws + 295190528);    // [32768][3072] bf16 (dead
                                                  //   before FC1; a1 aliases it)
  // high-water: 496,517,120 bytes (= proven bound; a1 ends exactly there)

  const dim3 tb(256);
  const dim3 tb512(512);

  // weights -> bf16 transposed (wq/wk/wv in one 3-deep launch)
  transpose_cvt3<<<dim3(32, 32, 3), tb, 0, stream>>>(wq, wk, wv, wqkvT);
  transpose_cvt<<<dim3(32, 32), tb, 0, stream>>>(wo, woT, 1024, 1024);
  transpose_cvt<<<dim3(128, 32), tb, 0, stream>>>(fc1_w, fc1T, 1024, 4096);
  transpose_cvt<<<dim3(32, 128), tb, 0, stream>>>(fc2_w, fc2T, 4096, 1024);

  // LN1: src (fp32) -> h (bf16)
  ln_kernel<<<32768, tb, 0, stream>>>(src, ln1_w, ln1_b, hbuf);

  // QKV projection + phi on Q,K   (M=32768, N=3072, K=1024; gx=128, gy=12)
  gemm256<EPI_QKV><<<dim3(1536), tb512, 0, stream>>>(
      hbuf, 1024, wqkvT, 1024, 3072, 128, nullptr, nullptr, qkv);

  // kv / ksum: partial reduce (v3) -> finalize (bf16, transposed, swizzled)
  kv_reduce<<<1024, tb, 0, stream>>>(qkv, kv_part, ksum_part);
  kv_finalize<<<256, tb, 0, stream>>>(kv_part, ksum_part, kvT_g, ksum_f);

  // attention apply via MFMA -> ao (hbuf)
  attn_apply_mfma<<<2048, tb, 0, stream>>>(qkv, kvT_g, ksum_f, hbuf);

  // O projection + residual(src fp32) -> src2b (bf16)  (gx=128, gy=4)
  gemm256<EPI_RES><<<dim3(512), tb512, 0, stream>>>(
      hbuf, 1024, woT, 1024, 1024, 128, nullptr, src, src2b);

  // LN2: src2b (bf16) -> h2 (bf16, reuse hbuf)
  ln_kernel_b<<<32768, tb, 0, stream>>>(src2b, ln2_w, ln2_b, hbuf);

  // MLP, single pass over all 32768 rows (a1 aliases dead qkv region)
  // FC1: M=32768, N=4096, K=1024; gx=128, gy=16 -> grid 2048
  gemm256<EPI_GELU><<<dim3(2048), tb512, 0, stream>>>(
      hbuf, 1024, fc1T, 1024, 4096, 128, fc1_b, nullptr, a1);
  // FC2: M=32768, N=1024, K=4096; gx=128, gy=4 -> grid 512 ; bf16 residual
  gemm256<EPI_FC2><<<dim3(512), tb512, 0, stream>>>(
      a1, 4096, fc2T, 4096, 1024, 128, fc2_b, src2b, (float*)d_out);
}